// Round 1
// baseline (524.068 us; speedup 1.0000x reference)
//
#include <hip/hip_runtime.h>

typedef float f4 __attribute__((ext_vector_type(4)));
typedef float f2 __attribute__((ext_vector_type(2)));

// ---- index loader: handles int32 or int64 edge/batch arrays ----
__device__ __forceinline__ int ld_idx(const void* p, int i, int is64){
  if (is64) return (int)((const long long*)p)[i];
  return ((const int*)p)[i];
}

// Detect dtype of edge_index: if int64 (little-endian), every odd 32-bit word
// (high half of each value < 50000) is zero. For int32, odd words are random
// src/dst values -> P(all 1024 zero) ~ 0.
__global__ void detect_k(const unsigned int* __restrict__ e_raw, int* __restrict__ flag){
  __shared__ int any;
  if (threadIdx.x == 0) any = 0;
  __syncthreads();
  int nz = 0;
  for (int i = threadIdx.x; i < 1024; i += 256) nz |= (e_raw[2*i + 1] != 0u);
  if (nz) any = 1;               // benign race: all writers store 1
  __syncthreads();
  if (threadIdx.x == 0) flag[0] = (any == 0) ? 1 : 0;   // 1 => int64
}

// histogram of dst (degree counts) + batch conversion + graph-size histogram
__global__ void hist_k(const void* __restrict__ eidx, const void* __restrict__ batchp,
                       const int* __restrict__ flag, int* __restrict__ degcnt,
                       int* __restrict__ batch32, int* __restrict__ gcount,
                       int n, int e){
  int idx = blockIdx.x*256 + threadIdx.x;
  int is64 = flag[0];
  if (idx < e){
    int d = ld_idx(eidx, e + idx, is64);   // dst row of edge_index
    atomicAdd(&degcnt[d], 1);
  }
  if (idx < n){
    int b = ld_idx(batchp, idx, is64);
    batch32[idx] = b;
    atomicAdd(&gcount[b], 1);
  }
}

__global__ void dinv_k(const int* __restrict__ degcnt, float* __restrict__ dinv, int n){
  int i = blockIdx.x*256 + threadIdx.x;
  if (i < n) dinv[i] = rsqrtf((float)degcnt[i] + 1.0f);
}

// ---- two-level exclusive scan of degcnt -> rowptr ----
__global__ void scan_a(const int* __restrict__ degcnt, int* __restrict__ rowptr,
                       int* __restrict__ bsum, int n){
  __shared__ int sh[256];
  int tid = threadIdx.x;
  int i = blockIdx.x*256 + tid;
  int v = (i < n) ? degcnt[i] : 0;
  sh[tid] = v; __syncthreads();
  for (int off = 1; off < 256; off <<= 1){
    int t = (tid >= off) ? sh[tid - off] : 0;
    __syncthreads();
    sh[tid] += t;
    __syncthreads();
  }
  if (i < n) rowptr[i] = sh[tid] - v;          // block-local exclusive
  if (tid == 255) bsum[blockIdx.x] = sh[255];  // block total
}

__global__ void scan_b(int* __restrict__ bsum, int nb){
  __shared__ int sh[256];
  int tid = threadIdx.x;
  int v = (tid < nb) ? bsum[tid] : 0;
  sh[tid] = v; __syncthreads();
  for (int off = 1; off < 256; off <<= 1){
    int t = (tid >= off) ? sh[tid - off] : 0;
    __syncthreads();
    sh[tid] += t;
    __syncthreads();
  }
  if (tid < nb) bsum[tid] = sh[tid] - v;       // exclusive block offsets
}

__global__ void scan_c(int* __restrict__ rowptr, const int* __restrict__ bsum, int n, int e){
  int i = blockIdx.x*256 + threadIdx.x;
  if (i < n) rowptr[i] += bsum[i >> 8];
  if (i == n) rowptr[n] = e;
}

// scatter edges into CSR order (src list sorted by dst)
__global__ void fill_k(const void* __restrict__ eidx, const int* __restrict__ flag,
                       const int* __restrict__ rowptr, int* __restrict__ cursor,
                       int* __restrict__ esrcS, int e){
  int idx = blockIdx.x*256 + threadIdx.x;
  if (idx >= e) return;
  int is64 = flag[0];
  int s = ld_idx(eidx, idx, is64);
  int d = ld_idx(eidx, e + idx, is64);
  int pos = rowptr[d] + atomicAdd(&cursor[d], 1);
  esrcS[pos] = s;
}

// ---- GEMM: Y[n,NC] = X[n,128] @ W[128,NC], W staged in LDS ----
template<int NC>
__global__ __launch_bounds__(256) void gemm_k(const float* __restrict__ X,
                                              const float* __restrict__ W,
                                              float* __restrict__ Y, int n){
  constexpr int NCQ = NC/4;        // float4 groups per row: 32 or 16
  constexpr int ROWG = 256/NCQ;    // row groups per block: 8 or 16
  constexpr int RPB  = ROWG*4;     // rows per block: 32 or 64
  __shared__ f4 Wl[128*NCQ];       // 64KB (NC=128) or 32KB (NC=64)
  const f4* W4 = (const f4*)W;
  for (int idx = threadIdx.x; idx < 128*NCQ; idx += 256) Wl[idx] = W4[idx];
  __syncthreads();
  const int cq = threadIdx.x % NCQ;
  const int rg = threadIdx.x / NCQ;
  const f4* X4 = (const f4*)X;     // row stride = 32 f4
  int rows[4];
#pragma unroll
  for (int j = 0; j < 4; ++j){
    int r = blockIdx.x*RPB + rg + j*ROWG;
    rows[j] = (r < n) ? r : (n - 1);   // clamp: branchless, store guarded below
  }
  f4 acc[4];
#pragma unroll
  for (int j = 0; j < 4; ++j) acc[j] = 0.0f;
  for (int kk = 0; kk < 32; ++kk){
    f4 xv[4];
#pragma unroll
    for (int j = 0; j < 4; ++j) xv[j] = X4[rows[j]*32 + kk];
#pragma unroll
    for (int t = 0; t < 4; ++t){
      f4 w4 = Wl[(kk*4 + t)*NCQ + cq];
#pragma unroll
      for (int j = 0; j < 4; ++j) acc[j] += xv[j][t] * w4;
    }
  }
  f4* Y4 = (f4*)Y;
#pragma unroll
  for (int j = 0; j < 4; ++j){
    int r = blockIdx.x*RPB + rg + j*ROWG;
    if (r < n) Y4[r*NCQ + cq] = acc[j];
  }
}

// ---- CSR aggregation + bias + relu: one wave per node ----
template<int NC>
__global__ __launch_bounds__(256) void agg_k(const float* __restrict__ HW,
                                             const float* __restrict__ dinv,
                                             const int* __restrict__ rowptr,
                                             const int* __restrict__ esrcS,
                                             const float* __restrict__ bias,
                                             float* __restrict__ Hout, int n){
  int wid  = (blockIdx.x*256 + threadIdx.x) >> 6;
  int lane = threadIdx.x & 63;
  if (wid >= n) return;
  float di = dinv[wid];
  int beg = rowptr[wid], end = rowptr[wid + 1];
  if (NC == 128){
    const f2* HW2 = (const f2*)HW;
    f2 acc = HW2[(size_t)wid*64 + lane] * (di*di);   // self-loop term
    for (int j = beg; j < end; ++j){
      int s = esrcS[j];
      float w = dinv[s] * di;
      acc += HW2[(size_t)s*64 + lane] * w;
    }
    f2 bb = ((const f2*)bias)[lane];
    acc += bb;
    acc[0] = fmaxf(acc[0], 0.0f);
    acc[1] = fmaxf(acc[1], 0.0f);
    ((f2*)Hout)[(size_t)wid*64 + lane] = acc;
  } else {
    float acc = HW[(size_t)wid*64 + lane] * (di*di);
    for (int j = beg; j < end; ++j){
      int s = esrcS[j];
      acc += HW[(size_t)s*64 + lane] * (dinv[s] * di);
    }
    acc = fmaxf(acc + bias[lane], 0.0f);
    Hout[(size_t)wid*64 + lane] = acc;
  }
}

// ---- mean pool: batch is sorted -> run-length accumulate, few atomics ----
__global__ __launch_bounds__(256) void pool_k(const float* __restrict__ H2,
                                              const int* __restrict__ batch32,
                                              float* __restrict__ outsum, int n){
  int wid  = (blockIdx.x*256 + threadIdx.x) >> 6;
  int lane = threadIdx.x & 63;
  int start = wid * 128;
  if (start >= n) return;
  int end = min(start + 128, n);
  int gcur = batch32[start];
  float acc = 0.0f;
  for (int i = start; i < end; ++i){
    int gi = batch32[i];                     // wave-uniform
    if (gi != gcur){
      unsafeAtomicAdd(&outsum[gcur*64 + lane], acc);
      acc = 0.0f; gcur = gi;
    }
    acc += H2[(size_t)i*64 + lane];
  }
  unsafeAtomicAdd(&outsum[gcur*64 + lane], acc);
}

__global__ void fin_k(float* __restrict__ out, const int* __restrict__ gcount, int total){
  int idx = blockIdx.x*256 + threadIdx.x;
  if (idx < total){
    int gidx = idx >> 6;
    float c = (float)gcount[gidx];
    out[idx] = out[idx] / fmaxf(c, 1.0f);
  }
}

extern "C" void kernel_launch(void* const* d_in, const int* in_sizes, int n_in,
                              void* d_out, int out_size, void* d_ws, size_t ws_size,
                              hipStream_t stream){
  const float* x    = (const float*)d_in[0];
  const float* W1   = (const float*)d_in[1];
  const float* b1   = (const float*)d_in[2];
  const float* W2   = (const float*)d_in[3];
  const float* b2   = (const float*)d_in[4];
  const void*  eidx = d_in[5];
  const void*  batchp = d_in[6];
  const int n = in_sizes[0] / 128;    // 50000
  const int e = in_sizes[5] / 2;      // 800000
  const int g = out_size / 64;        // 64 graphs
  float* out = (float*)d_out;

  // ---- workspace layout ----
  char* w = (char*)d_ws;
  int* flag    = (int*)w;                 // 64 ints reserved
  int* degcnt  = flag + 64;               // n   } contiguous,
  int* cursor  = degcnt + n;              // n   } zeroed with
  int* gcount  = cursor + n;              // g   } one memset
  int* rowptr  = gcount + g;              // n+1
  int* bsum    = rowptr + (n + 1);        // 256
  int* esrcS   = bsum + 256;              // e
  int* batch32 = esrcS + e;               // n
  float* dinv  = (float*)(batch32 + n);   // n
  size_t ofs = (size_t)((char*)(dinv + n) - w);
  ofs = (ofs + 255) & ~(size_t)255;
  float* HW = (float*)(w + ofs);          // n*128 f32 (HW1, reused for HW2)
  float* H  = HW + (size_t)n*128;         // n*128 f32 (h1, reused for h2)

  hipMemsetAsync(degcnt, 0, (size_t)(2*n + g)*sizeof(int), stream);
  hipMemsetAsync(out, 0, (size_t)out_size*sizeof(float), stream);

  const int nb = (n + 255)/256;
  const int eb = (e + 255)/256;

  detect_k<<<1, 256, 0, stream>>>((const unsigned int*)eidx, flag);
  hist_k<<<eb, 256, 0, stream>>>(eidx, batchp, flag, degcnt, batch32, gcount, n, e);
  dinv_k<<<nb, 256, 0, stream>>>(degcnt, dinv, n);
  scan_a<<<nb, 256, 0, stream>>>(degcnt, rowptr, bsum, n);
  scan_b<<<1, 256, 0, stream>>>(bsum, nb);
  scan_c<<<(n + 1 + 255)/256, 256, 0, stream>>>(rowptr, bsum, n, e);
  fill_k<<<eb, 256, 0, stream>>>(eidx, flag, rowptr, cursor, esrcS, e);

  gemm_k<128><<<(n + 31)/32, 256, 0, stream>>>(x, W1, HW, n);
  agg_k<128><<<(n + 3)/4, 256, 0, stream>>>(HW, dinv, rowptr, esrcS, b1, H, n);
  gemm_k<64><<<(n + 63)/64, 256, 0, stream>>>(H, W2, HW, n);
  agg_k<64><<<(n + 3)/4, 256, 0, stream>>>(HW, dinv, rowptr, esrcS, b2, H, n);

  int pw = (n + 127)/128;   // one wave per 128-node chunk
  pool_k<<<(pw + 3)/4, 256, 0, stream>>>(H, batch32, out, n);
  fin_k<<<(out_size + 255)/256, 256, 0, stream>>>(out, gcount, out_size);
}

// Round 2
// 349.390 us; speedup vs baseline: 1.5000x; 1.5000x over previous
//
#include <hip/hip_runtime.h>

typedef float f4 __attribute__((ext_vector_type(4)));
typedef float f2 __attribute__((ext_vector_type(2)));

// ---- index loader: handles int32 or int64 edge/batch arrays ----
__device__ __forceinline__ int ld_idx(const void* p, int i, int is64){
  if (is64) return (int)((const long long*)p)[i];
  return ((const int*)p)[i];
}

// Detect dtype of edge_index: if int64 (little-endian), every odd 32-bit word
// (high half of each value < n) is zero. For int32, odd words are random
// src/dst values -> P(all 1024 zero) ~ 0.
__global__ void detect_k(const unsigned int* __restrict__ e_raw, int* __restrict__ flag){
  __shared__ int any;
  if (threadIdx.x == 0) any = 0;
  __syncthreads();
  int nz = 0;
  for (int i = threadIdx.x; i < 1024; i += 256) nz |= (e_raw[2*i + 1] != 0u);
  if (nz) any = 1;               // benign race: all writers store 1
  __syncthreads();
  if (threadIdx.x == 0) flag[0] = (any == 0) ? 1 : 0;   // 1 => int64
}

// edge histogram (captures per-edge rank within dst) + batch conversion.
// NO same-address hotspots: 800K atomics spread over n counters.
__global__ void ehist_k(const void* __restrict__ eidx, const void* __restrict__ batchp,
                        const int* __restrict__ flag, int* __restrict__ degcnt,
                        int* __restrict__ erank, int wantRank,
                        int* __restrict__ batch32, int n, int e){
  int idx = blockIdx.x*256 + threadIdx.x;
  int is64 = flag[0];
  if (idx < e){
    int d = ld_idx(eidx, e + idx, is64);   // dst row of edge_index
    int r = atomicAdd(&degcnt[d], 1);
    if (wantRank) erank[idx] = r;
  }
  if (idx < n){
    batch32[idx] = (int)ld_idx(batchp, idx, is64);
  }
}

// graph sizes from sorted batch via binary search — zero atomics
__global__ void gcnt_k(const int* __restrict__ batch32, int* __restrict__ gcount,
                       int n, int g){
  __shared__ int starts[257];
  int t = threadIdx.x;
  if (t <= g){
    int lo = 0, hi = n;
    while (lo < hi){ int mid = (lo + hi) >> 1; if (batch32[mid] < t) lo = mid + 1; else hi = mid; }
    starts[t] = lo;
  }
  __syncthreads();
  if (t < g) gcount[t] = starts[t+1] - starts[t];
}

// ---- two-level exclusive scan of degcnt -> rowptr ----
__global__ void scan_a(const int* __restrict__ degcnt, int* __restrict__ rowptr,
                       int* __restrict__ bsum, int n){
  __shared__ int sh[256];
  int tid = threadIdx.x;
  int i = blockIdx.x*256 + tid;
  int v = (i < n) ? degcnt[i] : 0;
  sh[tid] = v; __syncthreads();
  for (int off = 1; off < 256; off <<= 1){
    int t = (tid >= off) ? sh[tid - off] : 0;
    __syncthreads();
    sh[tid] += t;
    __syncthreads();
  }
  if (i < n) rowptr[i] = sh[tid] - v;          // block-local exclusive
  if (tid == 255) bsum[blockIdx.x] = sh[255];  // block total
}

__global__ void scan_b(int* __restrict__ bsum, int nb){
  __shared__ int sh[256];
  int tid = threadIdx.x;
  int v = (tid < nb) ? bsum[tid] : 0;
  sh[tid] = v; __syncthreads();
  for (int off = 1; off < 256; off <<= 1){
    int t = (tid >= off) ? sh[tid - off] : 0;
    __syncthreads();
    sh[tid] += t;
    __syncthreads();
  }
  if (tid < nb) bsum[tid] = sh[tid] - v;       // exclusive block offsets
}

// finalize rowptr + compute deg_inv_sqrt (fused)
__global__ void scan_c(int* __restrict__ rowptr, const int* __restrict__ bsum,
                       const int* __restrict__ degcnt, float* __restrict__ dinv,
                       int n, int e){
  int i = blockIdx.x*256 + threadIdx.x;
  if (i < n){
    rowptr[i] += bsum[i >> 8];
    dinv[i] = rsqrtf((float)degcnt[i] + 1.0f);
  }
  if (i == n) rowptr[n] = e;
}

// scatter edges into CSR order using precomputed ranks — atomic-free
__global__ void fillr_k(const void* __restrict__ eidx, const int* __restrict__ flag,
                        const int* __restrict__ rowptr, const int* __restrict__ erank,
                        int* __restrict__ esrcS, int e){
  int idx = blockIdx.x*256 + threadIdx.x;
  if (idx >= e) return;
  int is64 = flag[0];
  int s = ld_idx(eidx, idx, is64);
  int d = ld_idx(eidx, e + idx, is64);
  esrcS[rowptr[d] + erank[idx]] = s;
}

// fallback scatter (atomic cursor) if ws is too small for erank
__global__ void fill_k(const void* __restrict__ eidx, const int* __restrict__ flag,
                       const int* __restrict__ rowptr, int* __restrict__ cursor,
                       int* __restrict__ esrcS, int e){
  int idx = blockIdx.x*256 + threadIdx.x;
  if (idx >= e) return;
  int is64 = flag[0];
  int s = ld_idx(eidx, idx, is64);
  int d = ld_idx(eidx, e + idx, is64);
  int pos = rowptr[d] + atomicAdd(&cursor[d], 1);
  esrcS[pos] = s;
}

// ---- GEMM: Y[n,NC] = X[n,128] @ W[128,NC], W staged in LDS ----
template<int NC>
__global__ __launch_bounds__(256) void gemm_k(const float* __restrict__ X,
                                              const float* __restrict__ W,
                                              float* __restrict__ Y, int n){
  constexpr int NCQ = NC/4;        // float4 groups per row: 32 or 16
  constexpr int ROWG = 256/NCQ;    // row groups per block: 8 or 16
  constexpr int RPB  = ROWG*4;     // rows per block: 32 or 64
  __shared__ f4 Wl[128*NCQ];       // 64KB (NC=128) or 32KB (NC=64)
  const f4* W4 = (const f4*)W;
  for (int idx = threadIdx.x; idx < 128*NCQ; idx += 256) Wl[idx] = W4[idx];
  __syncthreads();
  const int cq = threadIdx.x % NCQ;
  const int rg = threadIdx.x / NCQ;
  const f4* X4 = (const f4*)X;     // row stride = 32 f4
  int rows[4];
#pragma unroll
  for (int j = 0; j < 4; ++j){
    int r = blockIdx.x*RPB + rg + j*ROWG;
    rows[j] = (r < n) ? r : (n - 1);   // clamp: branchless, store guarded below
  }
  f4 acc[4];
#pragma unroll
  for (int j = 0; j < 4; ++j) acc[j] = 0.0f;
  for (int kk = 0; kk < 32; ++kk){
    f4 xv[4];
#pragma unroll
    for (int j = 0; j < 4; ++j) xv[j] = X4[rows[j]*32 + kk];
#pragma unroll
    for (int t = 0; t < 4; ++t){
      f4 w4 = Wl[(kk*4 + t)*NCQ + cq];
#pragma unroll
      for (int j = 0; j < 4; ++j) acc[j] += xv[j][t] * w4;
    }
  }
  f4* Y4 = (f4*)Y;
#pragma unroll
  for (int j = 0; j < 4; ++j){
    int r = blockIdx.x*RPB + rg + j*ROWG;
    if (r < n) Y4[r*NCQ + cq] = acc[j];
  }
}

// ---- CSR aggregation + bias + relu: one wave per node ----
template<int NC>
__global__ __launch_bounds__(256) void agg_k(const float* __restrict__ HW,
                                             const float* __restrict__ dinv,
                                             const int* __restrict__ rowptr,
                                             const int* __restrict__ esrcS,
                                             const float* __restrict__ bias,
                                             float* __restrict__ Hout, int n){
  int wid  = (blockIdx.x*256 + threadIdx.x) >> 6;
  int lane = threadIdx.x & 63;
  if (wid >= n) return;
  float di = dinv[wid];
  int beg = rowptr[wid], end = rowptr[wid + 1];
  if (NC == 128){
    const f2* HW2 = (const f2*)HW;
    f2 acc = HW2[(size_t)wid*64 + lane] * (di*di);   // self-loop term
    for (int j = beg; j < end; ++j){
      int s = esrcS[j];
      float w = dinv[s] * di;
      acc += HW2[(size_t)s*64 + lane] * w;
    }
    f2 bb = ((const f2*)bias)[lane];
    acc += bb;
    acc[0] = fmaxf(acc[0], 0.0f);
    acc[1] = fmaxf(acc[1], 0.0f);
    ((f2*)Hout)[(size_t)wid*64 + lane] = acc;
  } else {
    float acc = HW[(size_t)wid*64 + lane] * (di*di);
    for (int j = beg; j < end; ++j){
      int s = esrcS[j];
      acc += HW[(size_t)s*64 + lane] * (dinv[s] * di);
    }
    acc = fmaxf(acc + bias[lane], 0.0f);
    Hout[(size_t)wid*64 + lane] = acc;
  }
}

// ---- mean pool: batch is sorted -> run-length accumulate, few atomics ----
__global__ __launch_bounds__(256) void pool_k(const float* __restrict__ H2,
                                              const int* __restrict__ batch32,
                                              float* __restrict__ outsum, int n){
  int wid  = (blockIdx.x*256 + threadIdx.x) >> 6;
  int lane = threadIdx.x & 63;
  int start = wid * 128;
  if (start >= n) return;
  int end = min(start + 128, n);
  int gcur = batch32[start];
  float acc = 0.0f;
  for (int i = start; i < end; ++i){
    int gi = batch32[i];                     // wave-uniform
    if (gi != gcur){
      unsafeAtomicAdd(&outsum[gcur*64 + lane], acc);
      acc = 0.0f; gcur = gi;
    }
    acc += H2[(size_t)i*64 + lane];
  }
  unsafeAtomicAdd(&outsum[gcur*64 + lane], acc);
}

__global__ void fin_k(float* __restrict__ out, const int* __restrict__ gcount, int total){
  int idx = blockIdx.x*256 + threadIdx.x;
  if (idx < total){
    int gidx = idx >> 6;
    float c = (float)gcount[gidx];
    out[idx] = out[idx] / fmaxf(c, 1.0f);
  }
}

extern "C" void kernel_launch(void* const* d_in, const int* in_sizes, int n_in,
                              void* d_out, int out_size, void* d_ws, size_t ws_size,
                              hipStream_t stream){
  const float* x    = (const float*)d_in[0];
  const float* W1   = (const float*)d_in[1];
  const float* b1   = (const float*)d_in[2];
  const float* W2   = (const float*)d_in[3];
  const float* b2   = (const float*)d_in[4];
  const void*  eidx = d_in[5];
  const void*  batchp = d_in[6];
  const int n = in_sizes[0] / 128;    // 50000
  const int e = in_sizes[5] / 2;      // 800000
  const int g = out_size / 64;        // 64 graphs
  float* out = (float*)d_out;

  // ---- workspace layout ----
  char* w = (char*)d_ws;
  int* flag    = (int*)w;                 // 64 ints reserved
  int* degcnt  = flag + 64;               // n (memset 0)
  int* gcount  = degcnt + n;              // g (fully written by gcnt_k)
  int* rowptr  = gcount + g;              // n+1
  int* bsum    = rowptr + (n + 1);        // 256
  // erank path needs e ints here; fallback cursor path needs n ints
  size_t fixedI = 64 + (size_t)n + g + (n + 1) + 256;
  size_t needA  = (fixedI + (size_t)e + e + n + n) * 4 + 512
                + (size_t)n * 128 * 2 * sizeof(float);
  const int useRank = (ws_size >= needA);
  int* erank   = bsum + 256;              // e ints (A) or n ints as cursor (B)
  int* esrcS   = erank + (useRank ? e : n);
  int* batch32 = esrcS + e;               // n
  float* dinv  = (float*)(batch32 + n);   // n
  size_t ofs = (size_t)((char*)(dinv + n) - w);
  ofs = (ofs + 255) & ~(size_t)255;
  float* HW = (float*)(w + ofs);          // n*128 f32 (HW1, reused for HW2)
  float* H  = HW + (size_t)n*128;         // n*128 f32 (h1, reused for h2)

  hipMemsetAsync(degcnt, 0, (size_t)n*sizeof(int), stream);
  if (!useRank) hipMemsetAsync(erank, 0, (size_t)n*sizeof(int), stream); // cursor
  hipMemsetAsync(out, 0, (size_t)out_size*sizeof(float), stream);

  const int nb = (n + 255)/256;
  const int m  = (e > n) ? e : n;
  const int mb = (m + 255)/256;
  const int eb = (e + 255)/256;

  detect_k<<<1, 256, 0, stream>>>((const unsigned int*)eidx, flag);
  ehist_k<<<mb, 256, 0, stream>>>(eidx, batchp, flag, degcnt, erank, useRank,
                                  batch32, n, e);
  gcnt_k<<<1, 256, 0, stream>>>(batch32, gcount, n, g);
  scan_a<<<nb, 256, 0, stream>>>(degcnt, rowptr, bsum, n);
  scan_b<<<1, 256, 0, stream>>>(bsum, nb);
  scan_c<<<(n + 1 + 255)/256, 256, 0, stream>>>(rowptr, bsum, degcnt, dinv, n, e);
  if (useRank)
    fillr_k<<<eb, 256, 0, stream>>>(eidx, flag, rowptr, erank, esrcS, e);
  else
    fill_k<<<eb, 256, 0, stream>>>(eidx, flag, rowptr, erank /*cursor*/, esrcS, e);

  gemm_k<128><<<(n + 31)/32, 256, 0, stream>>>(x, W1, HW, n);
  agg_k<128><<<(n + 3)/4, 256, 0, stream>>>(HW, dinv, rowptr, esrcS, b1, H, n);
  gemm_k<64><<<(n + 63)/64, 256, 0, stream>>>(H, W2, HW, n);
  agg_k<64><<<(n + 3)/4, 256, 0, stream>>>(HW, dinv, rowptr, esrcS, b2, H, n);

  int pw = (n + 127)/128;   // one wave per 128-node chunk
  pool_k<<<(pw + 3)/4, 256, 0, stream>>>(H, batch32, out, n);
  fin_k<<<(out_size + 255)/256, 256, 0, stream>>>(out, gcount, out_size);
}

// Round 3
// 342.513 us; speedup vs baseline: 1.5301x; 1.0201x over previous
//
#include <hip/hip_runtime.h>

typedef float f4 __attribute__((ext_vector_type(4)));
typedef float f2 __attribute__((ext_vector_type(2)));
typedef unsigned short us4 __attribute__((ext_vector_type(4)));

// ---- bf16 helpers ----
__device__ __forceinline__ unsigned short f2bf(float f){
  unsigned u = __float_as_uint(f);
  return (unsigned short)((u + 0x7FFFu + ((u >> 16) & 1u)) >> 16);  // RNE
}
__device__ __forceinline__ float bflo(unsigned v){ return __uint_as_float(v << 16); }
__device__ __forceinline__ float bfhi(unsigned v){ return __uint_as_float(v & 0xFFFF0000u); }

// ---- index loader: handles int32 or int64 edge/batch arrays ----
__device__ __forceinline__ int ld_idx(const void* p, int i, int is64){
  if (is64) return (int)((const long long*)p)[i];
  return ((const int*)p)[i];
}

// Detect dtype of edge_index: int64 => every odd 32-bit word is zero.
__global__ void detect_k(const unsigned int* __restrict__ e_raw, int* __restrict__ flag){
  __shared__ int any;
  if (threadIdx.x == 0) any = 0;
  __syncthreads();
  int nz = 0;
  for (int i = threadIdx.x; i < 1024; i += 256) nz |= (e_raw[2*i + 1] != 0u);
  if (nz) any = 1;
  __syncthreads();
  if (threadIdx.x == 0) flag[0] = (any == 0) ? 1 : 0;   // 1 => int64
}

// edge histogram (captures per-edge rank within dst) + batch conversion.
__global__ void ehist_k(const void* __restrict__ eidx, const void* __restrict__ batchp,
                        const int* __restrict__ flag, int* __restrict__ degcnt,
                        int* __restrict__ erank, int wantRank,
                        int* __restrict__ batch32, int n, int e){
  int idx = blockIdx.x*256 + threadIdx.x;
  int is64 = flag[0];
  if (idx < e){
    int d = ld_idx(eidx, e + idx, is64);
    int r = atomicAdd(&degcnt[d], 1);
    if (wantRank) erank[idx] = r;
  }
  if (idx < n){
    batch32[idx] = (int)ld_idx(batchp, idx, is64);
  }
}

// graph sizes from sorted batch via binary search — zero atomics
__global__ void gcnt_k(const int* __restrict__ batch32, int* __restrict__ gcount,
                       int n, int g){
  __shared__ int starts[257];
  int t = threadIdx.x;
  if (t <= g){
    int lo = 0, hi = n;
    while (lo < hi){ int mid = (lo + hi) >> 1; if (batch32[mid] < t) lo = mid + 1; else hi = mid; }
    starts[t] = lo;
  }
  __syncthreads();
  if (t < g) gcount[t] = starts[t+1] - starts[t];
}

// ---- two-level exclusive scan of degcnt -> rowptr ----
__global__ void scan_a(const int* __restrict__ degcnt, int* __restrict__ rowptr,
                       int* __restrict__ bsum, int n){
  __shared__ int sh[256];
  int tid = threadIdx.x;
  int i = blockIdx.x*256 + tid;
  int v = (i < n) ? degcnt[i] : 0;
  sh[tid] = v; __syncthreads();
  for (int off = 1; off < 256; off <<= 1){
    int t = (tid >= off) ? sh[tid - off] : 0;
    __syncthreads();
    sh[tid] += t;
    __syncthreads();
  }
  if (i < n) rowptr[i] = sh[tid] - v;
  if (tid == 255) bsum[blockIdx.x] = sh[255];
}

__global__ void scan_b(int* __restrict__ bsum, int nb){
  __shared__ int sh[256];
  int tid = threadIdx.x;
  int v = (tid < nb) ? bsum[tid] : 0;
  sh[tid] = v; __syncthreads();
  for (int off = 1; off < 256; off <<= 1){
    int t = (tid >= off) ? sh[tid - off] : 0;
    __syncthreads();
    sh[tid] += t;
    __syncthreads();
  }
  if (tid < nb) bsum[tid] = sh[tid] - v;
}

// finalize rowptr + compute deg_inv_sqrt (fused)
__global__ void scan_c(int* __restrict__ rowptr, const int* __restrict__ bsum,
                       const int* __restrict__ degcnt, float* __restrict__ dinv,
                       int n, int e){
  int i = blockIdx.x*256 + threadIdx.x;
  if (i < n){
    rowptr[i] += bsum[i >> 8];
    dinv[i] = rsqrtf((float)degcnt[i] + 1.0f);
  }
  if (i == n) rowptr[n] = e;
}

// scatter edges into CSR order; pack (src, norm=dinv[s]*dinv[d]) per edge
__global__ void fillr_k(const void* __restrict__ eidx, const int* __restrict__ flag,
                        const int* __restrict__ rowptr, const int* __restrict__ erank,
                        const float* __restrict__ dinv, int2* __restrict__ epack, int e){
  int idx = blockIdx.x*256 + threadIdx.x;
  if (idx >= e) return;
  int is64 = flag[0];
  int s = ld_idx(eidx, idx, is64);
  int d = ld_idx(eidx, e + idx, is64);
  int2 pk; pk.x = s; pk.y = __float_as_int(dinv[s] * dinv[d]);
  epack[rowptr[d] + erank[idx]] = pk;
}

// fallback scatter (atomic cursor) if ws too small for erank
__global__ void fill_k(const void* __restrict__ eidx, const int* __restrict__ flag,
                       const int* __restrict__ rowptr, int* __restrict__ cursor,
                       const float* __restrict__ dinv, int2* __restrict__ epack, int e){
  int idx = blockIdx.x*256 + threadIdx.x;
  if (idx >= e) return;
  int is64 = flag[0];
  int s = ld_idx(eidx, idx, is64);
  int d = ld_idx(eidx, e + idx, is64);
  int pos = rowptr[d] + atomicAdd(&cursor[d], 1);
  int2 pk; pk.x = s; pk.y = __float_as_int(dinv[s] * dinv[d]);
  epack[pos] = pk;
}

// ---- GEMM: Yb[n,NC](bf16) = X[n,128](f32) @ W[128,NC], W staged in LDS ----
template<int NC>
__global__ __launch_bounds__(256) void gemm_k(const float* __restrict__ X,
                                              const float* __restrict__ W,
                                              unsigned short* __restrict__ Yb, int n){
  constexpr int NCQ = NC/4;
  constexpr int ROWG = 256/NCQ;
  constexpr int RPB  = ROWG*4;
  __shared__ f4 Wl[128*NCQ];
  const f4* W4 = (const f4*)W;
  for (int idx = threadIdx.x; idx < 128*NCQ; idx += 256) Wl[idx] = W4[idx];
  __syncthreads();
  const int cq = threadIdx.x % NCQ;
  const int rg = threadIdx.x / NCQ;
  const f4* X4 = (const f4*)X;
  int rows[4];
#pragma unroll
  for (int j = 0; j < 4; ++j){
    int r = blockIdx.x*RPB + rg + j*ROWG;
    rows[j] = (r < n) ? r : (n - 1);
  }
  f4 acc[4];
#pragma unroll
  for (int j = 0; j < 4; ++j) acc[j] = 0.0f;
  for (int kk = 0; kk < 32; ++kk){
    f4 xv[4];
#pragma unroll
    for (int j = 0; j < 4; ++j) xv[j] = X4[rows[j]*32 + kk];
#pragma unroll
    for (int t = 0; t < 4; ++t){
      f4 w4 = Wl[(kk*4 + t)*NCQ + cq];
#pragma unroll
      for (int j = 0; j < 4; ++j) acc[j] += xv[j][t] * w4;
    }
  }
  us4* Y4 = (us4*)Yb;
#pragma unroll
  for (int j = 0; j < 4; ++j){
    int r = blockIdx.x*RPB + rg + j*ROWG;
    if (r < n){
      us4 o;
#pragma unroll
      for (int t = 0; t < 4; ++t) o[t] = f2bf(acc[j][t]);
      Y4[r*NCQ + cq] = o;
    }
  }
}

// ---- CSR aggregation + bias + relu: one wave per node, bf16 gathers ----
template<int NC>
__global__ __launch_bounds__(256) void agg_k(const unsigned short* __restrict__ HWb,
                                             const float* __restrict__ dinv,
                                             const int* __restrict__ rowptr,
                                             const int2* __restrict__ epack,
                                             const float* __restrict__ bias,
                                             float* __restrict__ Hout, int n){
  int wid  = (blockIdx.x*256 + threadIdx.x) >> 6;
  int lane = threadIdx.x & 63;
  if (wid >= n) return;
  float di = dinv[wid];
  float di2 = di * di;
  int beg = rowptr[wid], end = rowptr[wid + 1];
  if (NC == 128){
    const unsigned* self = (const unsigned*)(HWb + (size_t)wid*128);
    unsigned sv = self[lane];
    f2 acc;
    acc[0] = bflo(sv) * di2;
    acc[1] = bfhi(sv) * di2;
    for (int j = beg; j < end; ++j){
      int2 pk = epack[j];
      float w = __int_as_float(pk.y);
      unsigned v = ((const unsigned*)(HWb + (size_t)pk.x*128))[lane];
      acc[0] += bflo(v) * w;
      acc[1] += bfhi(v) * w;
    }
    f2 bb = ((const f2*)bias)[lane];
    acc += bb;
    acc[0] = fmaxf(acc[0], 0.0f);
    acc[1] = fmaxf(acc[1], 0.0f);
    ((f2*)Hout)[(size_t)wid*64 + lane] = acc;
  } else {
    float acc = bflo((unsigned)HWb[(size_t)wid*64 + lane]) * di2;
    for (int j = beg; j < end; ++j){
      int2 pk = epack[j];
      float w = __int_as_float(pk.y);
      acc += bflo((unsigned)HWb[(size_t)pk.x*64 + lane]) * w;
    }
    acc = fmaxf(acc + bias[lane], 0.0f);
    Hout[(size_t)wid*64 + lane] = acc;
  }
}

// ---- mean pool: batch is sorted -> run-length accumulate, few atomics ----
__global__ __launch_bounds__(256) void pool_k(const float* __restrict__ H2,
                                              const int* __restrict__ batch32,
                                              float* __restrict__ outsum, int n){
  int wid  = (blockIdx.x*256 + threadIdx.x) >> 6;
  int lane = threadIdx.x & 63;
  int start = wid * 128;
  if (start >= n) return;
  int end = min(start + 128, n);
  int gcur = batch32[start];
  float acc = 0.0f;
  for (int i = start; i < end; ++i){
    int gi = batch32[i];
    if (gi != gcur){
      unsafeAtomicAdd(&outsum[gcur*64 + lane], acc);
      acc = 0.0f; gcur = gi;
    }
    acc += H2[(size_t)i*64 + lane];
  }
  unsafeAtomicAdd(&outsum[gcur*64 + lane], acc);
}

__global__ void fin_k(float* __restrict__ out, const int* __restrict__ gcount, int total){
  int idx = blockIdx.x*256 + threadIdx.x;
  if (idx < total){
    int gidx = idx >> 6;
    float c = (float)gcount[gidx];
    out[idx] = out[idx] / fmaxf(c, 1.0f);
  }
}

extern "C" void kernel_launch(void* const* d_in, const int* in_sizes, int n_in,
                              void* d_out, int out_size, void* d_ws, size_t ws_size,
                              hipStream_t stream){
  const float* x    = (const float*)d_in[0];
  const float* W1   = (const float*)d_in[1];
  const float* b1   = (const float*)d_in[2];
  const float* W2   = (const float*)d_in[3];
  const float* b2   = (const float*)d_in[4];
  const void*  eidx = d_in[5];
  const void*  batchp = d_in[6];
  const int n = in_sizes[0] / 128;    // 50000
  const int e = in_sizes[5] / 2;      // 800000
  const int g = out_size / 64;        // 64 graphs
  float* out = (float*)d_out;

  // ---- workspace layout ----
  char* w = (char*)d_ws;
  int* flag    = (int*)w;                 // 64 ints
  int* degcnt  = flag + 64;               // n (memset 0)
  int* gcount  = degcnt + n;              // g
  int* rowptr  = gcount + g;              // n+1
  int* bsum    = rowptr + (n + 1);        // 256
  size_t fixedI = 64 + (size_t)n + g + (n + 1) + 256;
  // rank path: erank e + epack 2e + batch32 n + dinv n ints, + HWb + H
  size_t needA  = (fixedI + (size_t)e + 2*(size_t)e + n + n) * 4 + 512
                + (size_t)n * 128 * 2        /* HWb bf16 */
                + (size_t)n * 128 * 4;       /* H f32 */
  const int useRank = (ws_size >= needA);
  int*  erank  = bsum + 256;              // e ints (A) or n ints as cursor (B)
  int2* epack  = (int2*)(erank + (useRank ? e : n));   // e int2
  int* batch32 = (int*)(epack + e);       // n
  float* dinv  = (float*)(batch32 + n);   // n
  size_t ofs = (size_t)((char*)(dinv + n) - w);
  ofs = (ofs + 255) & ~(size_t)255;
  unsigned short* HWb = (unsigned short*)(w + ofs);   // n*128 bf16 (both layers)
  size_t ofs2 = ofs + (size_t)n * 128 * 2;
  ofs2 = (ofs2 + 255) & ~(size_t)255;
  float* H = (float*)(w + ofs2);          // n*128 f32 (h1, reused for h2)

  hipMemsetAsync(degcnt, 0, (size_t)n*sizeof(int), stream);
  if (!useRank) hipMemsetAsync(erank, 0, (size_t)n*sizeof(int), stream); // cursor
  hipMemsetAsync(out, 0, (size_t)out_size*sizeof(float), stream);

  const int nb = (n + 255)/256;
  const int m  = (e > n) ? e : n;
  const int mb = (m + 255)/256;
  const int eb = (e + 255)/256;

  detect_k<<<1, 256, 0, stream>>>((const unsigned int*)eidx, flag);
  ehist_k<<<mb, 256, 0, stream>>>(eidx, batchp, flag, degcnt, erank, useRank,
                                  batch32, n, e);
  gcnt_k<<<1, 256, 0, stream>>>(batch32, gcount, n, g);
  scan_a<<<nb, 256, 0, stream>>>(degcnt, rowptr, bsum, n);
  scan_b<<<1, 256, 0, stream>>>(bsum, nb);
  scan_c<<<(n + 1 + 255)/256, 256, 0, stream>>>(rowptr, bsum, degcnt, dinv, n, e);
  if (useRank)
    fillr_k<<<eb, 256, 0, stream>>>(eidx, flag, rowptr, erank, dinv, epack, e);
  else
    fill_k<<<eb, 256, 0, stream>>>(eidx, flag, rowptr, erank /*cursor*/, dinv, epack, e);

  gemm_k<128><<<(n + 31)/32, 256, 0, stream>>>(x, W1, HWb, n);
  agg_k<128><<<(n + 3)/4, 256, 0, stream>>>(HWb, dinv, rowptr, epack, b1, H, n);
  gemm_k<64><<<(n + 63)/64, 256, 0, stream>>>(H, W2, HWb, n);
  agg_k<64><<<(n + 3)/4, 256, 0, stream>>>(HWb, dinv, rowptr, epack, b2, H, n);

  int pw = (n + 127)/128;
  pool_k<<<(pw + 3)/4, 256, 0, stream>>>(H, batch32, out, n);
  fin_k<<<(out_size + 255)/256, 256, 0, stream>>>(out, gcount, out_size);
}

// Round 4
// 242.728 us; speedup vs baseline: 2.1591x; 1.4111x over previous
//
#include <hip/hip_runtime.h>

typedef float f4 __attribute__((ext_vector_type(4)));
typedef float f2 __attribute__((ext_vector_type(2)));
typedef unsigned short us4 __attribute__((ext_vector_type(4)));

// ---- bf16 helpers ----
__device__ __forceinline__ unsigned short f2bf(float f){
  unsigned u = __float_as_uint(f);
  return (unsigned short)((u + 0x7FFFu + ((u >> 16) & 1u)) >> 16);  // RNE
}
__device__ __forceinline__ float bflo(unsigned v){ return __uint_as_float(v << 16); }
__device__ __forceinline__ float bfhi(unsigned v){ return __uint_as_float(v & 0xFFFF0000u); }

// ---- index loader: handles int32 or int64 edge/batch arrays ----
__device__ __forceinline__ int ld_idx(const void* p, int i, int is64){
  if (is64) return (int)((const long long*)p)[i];
  return ((const int*)p)[i];
}

// Detect dtype of edge_index: int64 => every odd 32-bit word is zero.
__global__ void detect_k(const unsigned int* __restrict__ e_raw, int* __restrict__ flag){
  __shared__ int any;
  if (threadIdx.x == 0) any = 0;
  __syncthreads();
  int nz = 0;
  for (int i = threadIdx.x; i < 1024; i += 256) nz |= (e_raw[2*i + 1] != 0u);
  if (nz) any = 1;
  __syncthreads();
  if (threadIdx.x == 0) flag[0] = (any == 0) ? 1 : 0;   // 1 => int64
}

// edge histogram (captures per-edge rank within dst) + batch conversion.
__global__ void ehist_k(const void* __restrict__ eidx, const void* __restrict__ batchp,
                        const int* __restrict__ flag, int* __restrict__ degcnt,
                        int* __restrict__ erank, int wantRank,
                        int* __restrict__ batch32, int n, int e){
  int idx = blockIdx.x*256 + threadIdx.x;
  int is64 = flag[0];
  if (idx < e){
    int d = ld_idx(eidx, e + idx, is64);
    int r = atomicAdd(&degcnt[d], 1);
    if (wantRank) erank[idx] = r;
  }
  if (idx < n){
    batch32[idx] = (int)ld_idx(batchp, idx, is64);
  }
}

// graph sizes from sorted batch via binary search — zero atomics
__global__ void gcnt_k(const int* __restrict__ batch32, int* __restrict__ gcount,
                       int n, int g){
  __shared__ int starts[257];
  int t = threadIdx.x;
  if (t <= g){
    int lo = 0, hi = n;
    while (lo < hi){ int mid = (lo + hi) >> 1; if (batch32[mid] < t) lo = mid + 1; else hi = mid; }
    starts[t] = lo;
  }
  __syncthreads();
  if (t < g) gcount[t] = starts[t+1] - starts[t];
}

// ---- two-level exclusive scan of degcnt -> rowptr ----
__global__ void scan_a(const int* __restrict__ degcnt, int* __restrict__ rowptr,
                       int* __restrict__ bsum, int n){
  __shared__ int sh[256];
  int tid = threadIdx.x;
  int i = blockIdx.x*256 + tid;
  int v = (i < n) ? degcnt[i] : 0;
  sh[tid] = v; __syncthreads();
  for (int off = 1; off < 256; off <<= 1){
    int t = (tid >= off) ? sh[tid - off] : 0;
    __syncthreads();
    sh[tid] += t;
    __syncthreads();
  }
  if (i < n) rowptr[i] = sh[tid] - v;
  if (tid == 255) bsum[blockIdx.x] = sh[255];
}

__global__ void scan_b(int* __restrict__ bsum, int nb){
  __shared__ int sh[256];
  int tid = threadIdx.x;
  int v = (tid < nb) ? bsum[tid] : 0;
  sh[tid] = v; __syncthreads();
  for (int off = 1; off < 256; off <<= 1){
    int t = (tid >= off) ? sh[tid - off] : 0;
    __syncthreads();
    sh[tid] += t;
    __syncthreads();
  }
  if (tid < nb) bsum[tid] = sh[tid] - v;
}

// finalize rowptr + compute deg_inv_sqrt (fused)
__global__ void scan_c(int* __restrict__ rowptr, const int* __restrict__ bsum,
                       const int* __restrict__ degcnt, float* __restrict__ dinv,
                       int n, int e){
  int i = blockIdx.x*256 + threadIdx.x;
  if (i < n){
    rowptr[i] += bsum[i >> 8];
    dinv[i] = rsqrtf((float)degcnt[i] + 1.0f);
  }
  if (i == n) rowptr[n] = e;
}

// scatter edges into CSR order; pack (src, norm=dinv[s]*dinv[d]) per edge
__global__ void fillr_k(const void* __restrict__ eidx, const int* __restrict__ flag,
                        const int* __restrict__ rowptr, const int* __restrict__ erank,
                        const float* __restrict__ dinv, int2* __restrict__ epack, int e){
  int idx = blockIdx.x*256 + threadIdx.x;
  if (idx >= e) return;
  int is64 = flag[0];
  int s = ld_idx(eidx, idx, is64);
  int d = ld_idx(eidx, e + idx, is64);
  int2 pk; pk.x = s; pk.y = __float_as_int(dinv[s] * dinv[d]);
  epack[rowptr[d] + erank[idx]] = pk;
}

// fallback scatter (atomic cursor) if ws too small for erank
__global__ void fill_k(const void* __restrict__ eidx, const int* __restrict__ flag,
                       const int* __restrict__ rowptr, int* __restrict__ cursor,
                       const float* __restrict__ dinv, int2* __restrict__ epack, int e){
  int idx = blockIdx.x*256 + threadIdx.x;
  if (idx >= e) return;
  int is64 = flag[0];
  int s = ld_idx(eidx, idx, is64);
  int d = ld_idx(eidx, e + idx, is64);
  int pos = rowptr[d] + atomicAdd(&cursor[d], 1);
  int2 pk; pk.x = s; pk.y = __float_as_int(dinv[s] * dinv[d]);
  epack[pos] = pk;
}

// ---- GEMM: Yb[n,NC](bf16) = X[n,128](f32) @ W[128,NC], W staged in LDS ----
template<int NC>
__global__ __launch_bounds__(256) void gemm_k(const float* __restrict__ X,
                                              const float* __restrict__ W,
                                              unsigned short* __restrict__ Yb, int n){
  constexpr int NCQ = NC/4;
  constexpr int ROWG = 256/NCQ;
  constexpr int RPB  = ROWG*4;
  __shared__ f4 Wl[128*NCQ];
  const f4* W4 = (const f4*)W;
  for (int idx = threadIdx.x; idx < 128*NCQ; idx += 256) Wl[idx] = W4[idx];
  __syncthreads();
  const int cq = threadIdx.x % NCQ;
  const int rg = threadIdx.x / NCQ;
  const f4* X4 = (const f4*)X;
  int rows[4];
#pragma unroll
  for (int j = 0; j < 4; ++j){
    int r = blockIdx.x*RPB + rg + j*ROWG;
    rows[j] = (r < n) ? r : (n - 1);
  }
  f4 acc[4];
#pragma unroll
  for (int j = 0; j < 4; ++j) acc[j] = 0.0f;
  for (int kk = 0; kk < 32; ++kk){
    f4 xv[4];
#pragma unroll
    for (int j = 0; j < 4; ++j) xv[j] = X4[rows[j]*32 + kk];
#pragma unroll
    for (int t = 0; t < 4; ++t){
      f4 w4 = Wl[(kk*4 + t)*NCQ + cq];
#pragma unroll
      for (int j = 0; j < 4; ++j) acc[j] += xv[j][t] * w4;
    }
  }
  us4* Y4 = (us4*)Yb;
#pragma unroll
  for (int j = 0; j < 4; ++j){
    int r = blockIdx.x*RPB + rg + j*ROWG;
    if (r < n){
      us4 o;
#pragma unroll
      for (int t = 0; t < 4; ++t) o[t] = f2bf(acc[j][t]);
      Y4[r*NCQ + cq] = o;
    }
  }
}

// ---- CSR aggregation + bias + relu: one wave per node, bf16 gathers.
// Unroll-by-8 load-then-FMA so 8 gathers are in flight per wave (MLP), and
// readfirstlane forces epack loads onto the scalar path (s_load_dwordx16).
template<int NC>
__global__ __launch_bounds__(256) void agg_k(const unsigned short* __restrict__ HWb,
                                             const float* __restrict__ dinv,
                                             const int* __restrict__ rowptr,
                                             const int2* __restrict__ epack,
                                             const float* __restrict__ bias,
                                             float* __restrict__ Hout, int n){
  int wid  = (blockIdx.x*256 + threadIdx.x) >> 6;
  int lane = threadIdx.x & 63;
  if (wid >= n) return;
  wid = __builtin_amdgcn_readfirstlane(wid);        // wave-uniform -> SGPR
  float di = dinv[wid];
  float di2 = di * di;
  int beg = __builtin_amdgcn_readfirstlane(rowptr[wid]);
  int end = __builtin_amdgcn_readfirstlane(rowptr[wid + 1]);
  if (NC == 128){
    unsigned sv = ((const unsigned*)(HWb + (size_t)wid*128))[lane];
    f2 acc;
    acc[0] = bflo(sv) * di2;
    acc[1] = bfhi(sv) * di2;
    int j = beg;
    for (; j + 8 <= end; j += 8){
      unsigned v[8]; float wt[8];
#pragma unroll
      for (int t = 0; t < 8; ++t){
        int2 pk = epack[j + t];
        wt[t] = __int_as_float(pk.y);
        v[t] = ((const unsigned*)(HWb + (size_t)pk.x*128))[lane];
      }
#pragma unroll
      for (int t = 0; t < 8; ++t){
        acc[0] += bflo(v[t]) * wt[t];
        acc[1] += bfhi(v[t]) * wt[t];
      }
    }
    if (j + 4 <= end){
      unsigned v[4]; float wt[4];
#pragma unroll
      for (int t = 0; t < 4; ++t){
        int2 pk = epack[j + t];
        wt[t] = __int_as_float(pk.y);
        v[t] = ((const unsigned*)(HWb + (size_t)pk.x*128))[lane];
      }
#pragma unroll
      for (int t = 0; t < 4; ++t){
        acc[0] += bflo(v[t]) * wt[t];
        acc[1] += bfhi(v[t]) * wt[t];
      }
      j += 4;
    }
    for (; j < end; ++j){
      int2 pk = epack[j];
      float wt = __int_as_float(pk.y);
      unsigned v = ((const unsigned*)(HWb + (size_t)pk.x*128))[lane];
      acc[0] += bflo(v) * wt;
      acc[1] += bfhi(v) * wt;
    }
    f2 bb = ((const f2*)bias)[lane];
    acc += bb;
    acc[0] = fmaxf(acc[0], 0.0f);
    acc[1] = fmaxf(acc[1], 0.0f);
    ((f2*)Hout)[(size_t)wid*64 + lane] = acc;
  } else {
    float acc = bflo((unsigned)HWb[(size_t)wid*64 + lane]) * di2;
    int j = beg;
    for (; j + 8 <= end; j += 8){
      unsigned v[8]; float wt[8];
#pragma unroll
      for (int t = 0; t < 8; ++t){
        int2 pk = epack[j + t];
        wt[t] = __int_as_float(pk.y);
        v[t] = (unsigned)HWb[(size_t)pk.x*64 + lane];
      }
#pragma unroll
      for (int t = 0; t < 8; ++t) acc += bflo(v[t]) * wt[t];
    }
    if (j + 4 <= end){
      unsigned v[4]; float wt[4];
#pragma unroll
      for (int t = 0; t < 4; ++t){
        int2 pk = epack[j + t];
        wt[t] = __int_as_float(pk.y);
        v[t] = (unsigned)HWb[(size_t)pk.x*64 + lane];
      }
#pragma unroll
      for (int t = 0; t < 4; ++t) acc += bflo(v[t]) * wt[t];
      j += 4;
    }
    for (; j < end; ++j){
      int2 pk = epack[j];
      acc += bflo((unsigned)HWb[(size_t)pk.x*64 + lane]) * __int_as_float(pk.y);
    }
    acc = fmaxf(acc + bias[lane], 0.0f);
    Hout[(size_t)wid*64 + lane] = acc;
  }
}

// ---- mean pool: batch is sorted -> run-length accumulate, few atomics ----
__global__ __launch_bounds__(256) void pool_k(const float* __restrict__ H2,
                                              const int* __restrict__ batch32,
                                              float* __restrict__ outsum, int n){
  int wid  = (blockIdx.x*256 + threadIdx.x) >> 6;
  int lane = threadIdx.x & 63;
  int start = wid * 128;
  if (start >= n) return;
  int end = min(start + 128, n);
  int gcur = batch32[start];
  float acc = 0.0f;
  for (int i = start; i < end; ++i){
    int gi = batch32[i];
    if (gi != gcur){
      unsafeAtomicAdd(&outsum[gcur*64 + lane], acc);
      acc = 0.0f; gcur = gi;
    }
    acc += H2[(size_t)i*64 + lane];
  }
  unsafeAtomicAdd(&outsum[gcur*64 + lane], acc);
}

__global__ void fin_k(float* __restrict__ out, const int* __restrict__ gcount, int total){
  int idx = blockIdx.x*256 + threadIdx.x;
  if (idx < total){
    int gidx = idx >> 6;
    float c = (float)gcount[gidx];
    out[idx] = out[idx] / fmaxf(c, 1.0f);
  }
}

extern "C" void kernel_launch(void* const* d_in, const int* in_sizes, int n_in,
                              void* d_out, int out_size, void* d_ws, size_t ws_size,
                              hipStream_t stream){
  const float* x    = (const float*)d_in[0];
  const float* W1   = (const float*)d_in[1];
  const float* b1   = (const float*)d_in[2];
  const float* W2   = (const float*)d_in[3];
  const float* b2   = (const float*)d_in[4];
  const void*  eidx = d_in[5];
  const void*  batchp = d_in[6];
  const int n = in_sizes[0] / 128;    // 50000
  const int e = in_sizes[5] / 2;      // 800000
  const int g = out_size / 64;        // 64 graphs
  float* out = (float*)d_out;

  // ---- workspace layout ----
  char* w = (char*)d_ws;
  int* flag    = (int*)w;                 // 64 ints
  int* degcnt  = flag + 64;               // n (memset 0)
  int* gcount  = degcnt + n;              // g
  int* rowptr  = gcount + g;              // n+1
  int* bsum    = rowptr + (n + 1);        // 256
  size_t fixedI = 64 + (size_t)n + g + (n + 1) + 256;
  size_t needA  = (fixedI + (size_t)e + 2*(size_t)e + n + n) * 4 + 512
                + (size_t)n * 128 * 2        /* HWb bf16 */
                + (size_t)n * 128 * 4;       /* H f32 */
  const int useRank = (ws_size >= needA);
  int*  erank  = bsum + 256;              // e ints (A) or n ints as cursor (B)
  int2* epack  = (int2*)(erank + (useRank ? e : n));   // e int2
  int* batch32 = (int*)(epack + e);       // n
  float* dinv  = (float*)(batch32 + n);   // n
  size_t ofs = (size_t)((char*)(dinv + n) - w);
  ofs = (ofs + 255) & ~(size_t)255;
  unsigned short* HWb = (unsigned short*)(w + ofs);   // n*128 bf16 (both layers)
  size_t ofs2 = ofs + (size_t)n * 128 * 2;
  ofs2 = (ofs2 + 255) & ~(size_t)255;
  float* H = (float*)(w + ofs2);          // n*128 f32 (h1, reused for h2)

  hipMemsetAsync(degcnt, 0, (size_t)n*sizeof(int), stream);
  if (!useRank) hipMemsetAsync(erank, 0, (size_t)n*sizeof(int), stream); // cursor
  hipMemsetAsync(out, 0, (size_t)out_size*sizeof(float), stream);

  const int nb = (n + 255)/256;
  const int m  = (e > n) ? e : n;
  const int mb = (m + 255)/256;
  const int eb = (e + 255)/256;

  detect_k<<<1, 256, 0, stream>>>((const unsigned int*)eidx, flag);
  ehist_k<<<mb, 256, 0, stream>>>(eidx, batchp, flag, degcnt, erank, useRank,
                                  batch32, n, e);
  gcnt_k<<<1, 256, 0, stream>>>(batch32, gcount, n, g);
  scan_a<<<nb, 256, 0, stream>>>(degcnt, rowptr, bsum, n);
  scan_b<<<1, 256, 0, stream>>>(bsum, nb);
  scan_c<<<(n + 1 + 255)/256, 256, 0, stream>>>(rowptr, bsum, degcnt, dinv, n, e);
  if (useRank)
    fillr_k<<<eb, 256, 0, stream>>>(eidx, flag, rowptr, erank, dinv, epack, e);
  else
    fill_k<<<eb, 256, 0, stream>>>(eidx, flag, rowptr, erank /*cursor*/, dinv, epack, e);

  gemm_k<128><<<(n + 31)/32, 256, 0, stream>>>(x, W1, HWb, n);
  agg_k<128><<<(n + 3)/4, 256, 0, stream>>>(HWb, dinv, rowptr, epack, b1, H, n);
  gemm_k<64><<<(n + 63)/64, 256, 0, stream>>>(H, W2, HWb, n);
  agg_k<64><<<(n + 3)/4, 256, 0, stream>>>(HWb, dinv, rowptr, epack, b2, H, n);

  int pw = (n + 127)/128;
  pool_k<<<(pw + 3)/4, 256, 0, stream>>>(H, batch32, out, n);
  fin_k<<<(out_size + 255)/256, 256, 0, stream>>>(out, gcount, out_size);
}

// Round 5
// 200.658 us; speedup vs baseline: 2.6118x; 1.2097x over previous
//
#include <hip/hip_runtime.h>

typedef float f4 __attribute__((ext_vector_type(4)));
typedef float f2 __attribute__((ext_vector_type(2)));
typedef short s8 __attribute__((ext_vector_type(8)));

union FU { unsigned u[4]; s8 s; };

// packed f32x2 -> bf16x2 (RNE) in one instruction
__device__ __forceinline__ unsigned cvtpk(float lo, float hi){
  unsigned r;
  asm("v_cvt_pk_bf16_f32 %0, %1, %2" : "=v"(r) : "v"(lo), "v"(hi));
  return r;
}

// ---- bf16 helpers ----
__device__ __forceinline__ unsigned short f2bf(float f){
  unsigned u = __float_as_uint(f);
  return (unsigned short)((u + 0x7FFFu + ((u >> 16) & 1u)) >> 16);  // RNE
}
__device__ __forceinline__ float bflo(unsigned v){ return __uint_as_float(v << 16); }
__device__ __forceinline__ float bfhi(unsigned v){ return __uint_as_float(v & 0xFFFF0000u); }

// ---- index loader: handles int32 or int64 edge/batch arrays ----
__device__ __forceinline__ int ld_idx(const void* p, int i, int is64){
  if (is64) return (int)((const long long*)p)[i];
  return ((const int*)p)[i];
}

// Detect dtype of edge_index: int64 => every odd 32-bit word is zero.
__global__ void detect_k(const unsigned int* __restrict__ e_raw, int* __restrict__ flag){
  __shared__ int any;
  if (threadIdx.x == 0) any = 0;
  __syncthreads();
  int nz = 0;
  for (int i = threadIdx.x; i < 1024; i += 256) nz |= (e_raw[2*i + 1] != 0u);
  if (nz) any = 1;
  __syncthreads();
  if (threadIdx.x == 0) flag[0] = (any == 0) ? 1 : 0;   // 1 => int64
}

// edge histogram (captures per-edge rank within dst) + batch conversion.
__global__ void ehist_k(const void* __restrict__ eidx, const void* __restrict__ batchp,
                        const int* __restrict__ flag, int* __restrict__ degcnt,
                        int* __restrict__ erank, int wantRank,
                        int* __restrict__ batch32, int n, int e){
  int idx = blockIdx.x*256 + threadIdx.x;
  int is64 = flag[0];
  if (idx < e){
    int d = ld_idx(eidx, e + idx, is64);
    int r = atomicAdd(&degcnt[d], 1);
    if (wantRank) erank[idx] = r;
  }
  if (idx < n){
    batch32[idx] = (int)ld_idx(batchp, idx, is64);
  }
}

// graph sizes from sorted batch via binary search — zero atomics
__global__ void gcnt_k(const int* __restrict__ batch32, int* __restrict__ gcount,
                       int n, int g){
  __shared__ int starts[257];
  int t = threadIdx.x;
  if (t <= g){
    int lo = 0, hi = n;
    while (lo < hi){ int mid = (lo + hi) >> 1; if (batch32[mid] < t) lo = mid + 1; else hi = mid; }
    starts[t] = lo;
  }
  __syncthreads();
  if (t < g) gcount[t] = starts[t+1] - starts[t];
}

// ---- two-level exclusive scan of degcnt -> rowptr ----
__global__ void scan_a(const int* __restrict__ degcnt, int* __restrict__ rowptr,
                       int* __restrict__ bsum, int n){
  __shared__ int sh[256];
  int tid = threadIdx.x;
  int i = blockIdx.x*256 + tid;
  int v = (i < n) ? degcnt[i] : 0;
  sh[tid] = v; __syncthreads();
  for (int off = 1; off < 256; off <<= 1){
    int t = (tid >= off) ? sh[tid - off] : 0;
    __syncthreads();
    sh[tid] += t;
    __syncthreads();
  }
  if (i < n) rowptr[i] = sh[tid] - v;
  if (tid == 255) bsum[blockIdx.x] = sh[255];
}

__global__ void scan_b(int* __restrict__ bsum, int nb){
  __shared__ int sh[256];
  int tid = threadIdx.x;
  int v = (tid < nb) ? bsum[tid] : 0;
  sh[tid] = v; __syncthreads();
  for (int off = 1; off < 256; off <<= 1){
    int t = (tid >= off) ? sh[tid - off] : 0;
    __syncthreads();
    sh[tid] += t;
    __syncthreads();
  }
  if (tid < nb) bsum[tid] = sh[tid] - v;
}

// finalize rowptr + compute deg_inv_sqrt (fused)
__global__ void scan_c(int* __restrict__ rowptr, const int* __restrict__ bsum,
                       const int* __restrict__ degcnt, float* __restrict__ dinv,
                       int n, int e){
  int i = blockIdx.x*256 + threadIdx.x;
  if (i < n){
    rowptr[i] += bsum[i >> 8];
    dinv[i] = rsqrtf((float)degcnt[i] + 1.0f);
  }
  if (i == n) rowptr[n] = e;
}

// scatter edges into CSR order; pack (src, norm=dinv[s]*dinv[d]) per edge
__global__ void fillr_k(const void* __restrict__ eidx, const int* __restrict__ flag,
                        const int* __restrict__ rowptr, const int* __restrict__ erank,
                        const float* __restrict__ dinv, int2* __restrict__ epack, int e){
  int idx = blockIdx.x*256 + threadIdx.x;
  if (idx >= e) return;
  int is64 = flag[0];
  int s = ld_idx(eidx, idx, is64);
  int d = ld_idx(eidx, e + idx, is64);
  int2 pk; pk.x = s; pk.y = __float_as_int(dinv[s] * dinv[d]);
  epack[rowptr[d] + erank[idx]] = pk;
}

// fallback scatter (atomic cursor) if ws too small for erank
__global__ void fill_k(const void* __restrict__ eidx, const int* __restrict__ flag,
                       const int* __restrict__ rowptr, int* __restrict__ cursor,
                       const float* __restrict__ dinv, int2* __restrict__ epack, int e){
  int idx = blockIdx.x*256 + threadIdx.x;
  if (idx >= e) return;
  int is64 = flag[0];
  int s = ld_idx(eidx, idx, is64);
  int d = ld_idx(eidx, e + idx, is64);
  int pos = rowptr[d] + atomicAdd(&cursor[d], 1);
  int2 pk; pk.x = s; pk.y = __float_as_int(dinv[s] * dinv[d]);
  epack[pos] = pk;
}

// ---- MFMA GEMM: Yb[n,NC](bf16) = X[n,128](f32) @ W[128,NC](f32)
// 8 waves/block, M-tile=128, K=128. A staged in LDS (bf16, XOR-swizzled),
// B fragments held in registers per wave (W is L2-hot across all blocks).
template<int NC>
__global__ __launch_bounds__(512) void gemm_k(const float* __restrict__ X,
                                              const float* __restrict__ W,
                                              unsigned short* __restrict__ Yb, int n){
  constexpr int NCF = NC/16;      // col fragments: 8 (NC=128) or 4 (NC=64)
  constexpr int WPC = 8/NCF;      // wave row-groups: 1 or 2
  constexpr int RT  = 8/WPC;      // row tiles (16 rows) per wave: 8 or 4
  __shared__ int4 AldsV[2048];    // 32KB: A[row][k] bf16, byte ^= (row&7)<<4
  char* Alds = (char*)AldsV;
  const int tid  = threadIdx.x;
  const int wave = tid >> 6, lane = tid & 63;
  const int rb = blockIdx.x * 128;
  const f4* X4 = (const f4*)X;

  // B fragments: lane holds W[k][col], col = cbase+(lane&15), k = ks*32+kr0+j
  const int cbase = (wave % NCF) * 16;
  const int rt0   = (wave / NCF) * RT;
  const int col   = cbase + (lane & 15);
  const int kr0   = (lane >> 4) * 8;
  FU bu[4];
#pragma unroll
  for (int ks = 0; ks < 4; ++ks){
    float wv[8];
#pragma unroll
    for (int j = 0; j < 8; ++j) wv[j] = W[(size_t)(ks*32 + kr0 + j)*NC + col];
#pragma unroll
    for (int q = 0; q < 4; ++q) bu[ks].u[q] = cvtpk(wv[2*q], wv[2*q+1]);
  }

  // stage A tile (128 rows x 128 k) as bf16 into LDS
  for (int i = tid; i < 128*32; i += 512){
    int row = i >> 5, kq = i & 31;            // kq: float4 index along k
    int rsrc = rb + row; if (rsrc >= n) rsrc = n - 1;
    f4 xv = X4[(size_t)rsrc*32 + kq];
    unsigned lo = cvtpk(xv[0], xv[1]), hi = cvtpk(xv[2], xv[3]);
    int byte = (row*256 + kq*8) ^ ((row & 7) << 4);
    *reinterpret_cast<uint2*>(Alds + byte) = make_uint2(lo, hi);
  }
  __syncthreads();

  f4 acc[RT];
#pragma unroll
  for (int rt = 0; rt < RT; ++rt) acc[rt] = 0.0f;

#pragma unroll
  for (int rt = 0; rt < RT; ++rt){
    const int arow = (rt0 + rt)*16 + (lane & 15);
#pragma unroll
    for (int ks = 0; ks < 4; ++ks){
      int kb = ks*32 + kr0;
      int byte = (arow*256 + kb*2) ^ ((arow & 7) << 4);
      s8 a = *reinterpret_cast<const s8*>(Alds + byte);
      acc[rt] = __builtin_amdgcn_mfma_f32_16x16x32_bf16(a, bu[ks].s, acc[rt], 0, 0, 0);
    }
  }

  // C store: col = lane&15 offset, row = 4*(lane>>4) + r  (verified layout)
#pragma unroll
  for (int rt = 0; rt < RT; ++rt){
    int rowb = rb + (rt0 + rt)*16 + 4*(lane >> 4);
#pragma unroll
    for (int r = 0; r < 4; ++r){
      int row = rowb + r;
      if (row < n) Yb[(size_t)row*NC + col] = (unsigned short)cvtpk(acc[rt][r], acc[rt][r]);
    }
  }
}

// ---- CSR aggregation + bias + relu: one wave per node, bf16 gathers.
// Unroll-by-8 load-then-FMA so 8 gathers are in flight per wave (MLP).
template<int NC>
__global__ __launch_bounds__(256) void agg_k(const unsigned short* __restrict__ HWb,
                                             const float* __restrict__ dinv,
                                             const int* __restrict__ rowptr,
                                             const int2* __restrict__ epack,
                                             const float* __restrict__ bias,
                                             float* __restrict__ Hout, int n){
  int wid  = (blockIdx.x*256 + threadIdx.x) >> 6;
  int lane = threadIdx.x & 63;
  if (wid >= n) return;
  wid = __builtin_amdgcn_readfirstlane(wid);        // wave-uniform -> SGPR
  float di = dinv[wid];
  float di2 = di * di;
  int beg = __builtin_amdgcn_readfirstlane(rowptr[wid]);
  int end = __builtin_amdgcn_readfirstlane(rowptr[wid + 1]);
  if (NC == 128){
    unsigned sv = ((const unsigned*)(HWb + (size_t)wid*128))[lane];
    f2 acc;
    acc[0] = bflo(sv) * di2;
    acc[1] = bfhi(sv) * di2;
    int j = beg;
    for (; j + 8 <= end; j += 8){
      unsigned v[8]; float wt[8];
#pragma unroll
      for (int t = 0; t < 8; ++t){
        int2 pk = epack[j + t];
        wt[t] = __int_as_float(pk.y);
        v[t] = ((const unsigned*)(HWb + (size_t)pk.x*128))[lane];
      }
#pragma unroll
      for (int t = 0; t < 8; ++t){
        acc[0] += bflo(v[t]) * wt[t];
        acc[1] += bfhi(v[t]) * wt[t];
      }
    }
    if (j + 4 <= end){
      unsigned v[4]; float wt[4];
#pragma unroll
      for (int t = 0; t < 4; ++t){
        int2 pk = epack[j + t];
        wt[t] = __int_as_float(pk.y);
        v[t] = ((const unsigned*)(HWb + (size_t)pk.x*128))[lane];
      }
#pragma unroll
      for (int t = 0; t < 4; ++t){
        acc[0] += bflo(v[t]) * wt[t];
        acc[1] += bfhi(v[t]) * wt[t];
      }
      j += 4;
    }
    for (; j < end; ++j){
      int2 pk = epack[j];
      float wt = __int_as_float(pk.y);
      unsigned v = ((const unsigned*)(HWb + (size_t)pk.x*128))[lane];
      acc[0] += bflo(v) * wt;
      acc[1] += bfhi(v) * wt;
    }
    f2 bb = ((const f2*)bias)[lane];
    acc += bb;
    acc[0] = fmaxf(acc[0], 0.0f);
    acc[1] = fmaxf(acc[1], 0.0f);
    ((f2*)Hout)[(size_t)wid*64 + lane] = acc;
  } else {
    float acc = bflo((unsigned)HWb[(size_t)wid*64 + lane]) * di2;
    int j = beg;
    for (; j + 8 <= end; j += 8){
      unsigned v[8]; float wt[8];
#pragma unroll
      for (int t = 0; t < 8; ++t){
        int2 pk = epack[j + t];
        wt[t] = __int_as_float(pk.y);
        v[t] = (unsigned)HWb[(size_t)pk.x*64 + lane];
      }
#pragma unroll
      for (int t = 0; t < 8; ++t) acc += bflo(v[t]) * wt[t];
    }
    if (j + 4 <= end){
      unsigned v[4]; float wt[4];
#pragma unroll
      for (int t = 0; t < 4; ++t){
        int2 pk = epack[j + t];
        wt[t] = __int_as_float(pk.y);
        v[t] = (unsigned)HWb[(size_t)pk.x*64 + lane];
      }
#pragma unroll
      for (int t = 0; t < 4; ++t) acc += bflo(v[t]) * wt[t];
      j += 4;
    }
    for (; j < end; ++j){
      int2 pk = epack[j];
      acc += bflo((unsigned)HWb[(size_t)pk.x*64 + lane]) * __int_as_float(pk.y);
    }
    acc = fmaxf(acc + bias[lane], 0.0f);
    Hout[(size_t)wid*64 + lane] = acc;
  }
}

// ---- mean pool: batch is sorted -> run-length accumulate, few atomics ----
__global__ __launch_bounds__(256) void pool_k(const float* __restrict__ H2,
                                              const int* __restrict__ batch32,
                                              float* __restrict__ outsum, int n){
  int wid  = (blockIdx.x*256 + threadIdx.x) >> 6;
  int lane = threadIdx.x & 63;
  int start = wid * 128;
  if (start >= n) return;
  int end = min(start + 128, n);
  int gcur = batch32[start];
  float acc = 0.0f;
  for (int i = start; i < end; ++i){
    int gi = batch32[i];
    if (gi != gcur){
      unsafeAtomicAdd(&outsum[gcur*64 + lane], acc);
      acc = 0.0f; gcur = gi;
    }
    acc += H2[(size_t)i*64 + lane];
  }
  unsafeAtomicAdd(&outsum[gcur*64 + lane], acc);
}

__global__ void fin_k(float* __restrict__ out, const int* __restrict__ gcount, int total){
  int idx = blockIdx.x*256 + threadIdx.x;
  if (idx < total){
    int gidx = idx >> 6;
    float c = (float)gcount[gidx];
    out[idx] = out[idx] / fmaxf(c, 1.0f);
  }
}

extern "C" void kernel_launch(void* const* d_in, const int* in_sizes, int n_in,
                              void* d_out, int out_size, void* d_ws, size_t ws_size,
                              hipStream_t stream){
  const float* x    = (const float*)d_in[0];
  const float* W1   = (const float*)d_in[1];
  const float* b1   = (const float*)d_in[2];
  const float* W2   = (const float*)d_in[3];
  const float* b2   = (const float*)d_in[4];
  const void*  eidx = d_in[5];
  const void*  batchp = d_in[6];
  const int n = in_sizes[0] / 128;    // 50000
  const int e = in_sizes[5] / 2;      // 800000
  const int g = out_size / 64;        // 64 graphs
  float* out = (float*)d_out;

  // ---- workspace layout ----
  char* w = (char*)d_ws;
  int* flag    = (int*)w;                 // 64 ints
  int* degcnt  = flag + 64;               // n (memset 0)
  int* gcount  = degcnt + n;              // g
  int* rowptr  = gcount + g;              // n+1
  int* bsum    = rowptr + (n + 1);        // 256
  size_t fixedI = 64 + (size_t)n + g + (n + 1) + 256;
  size_t needA  = (fixedI + (size_t)e + 2*(size_t)e + n + n) * 4 + 512
                + (size_t)n * 128 * 2        /* HWb bf16 */
                + (size_t)n * 128 * 4;       /* H f32 */
  const int useRank = (ws_size >= needA);
  int*  erank  = bsum + 256;              // e ints (A) or n ints as cursor (B)
  int2* epack  = (int2*)(erank + (useRank ? e : n));   // e int2
  int* batch32 = (int*)(epack + e);       // n
  float* dinv  = (float*)(batch32 + n);   // n
  size_t ofs = (size_t)((char*)(dinv + n) - w);
  ofs = (ofs + 255) & ~(size_t)255;
  unsigned short* HWb = (unsigned short*)(w + ofs);   // n*128 bf16 (both layers)
  size_t ofs2 = ofs + (size_t)n * 128 * 2;
  ofs2 = (ofs2 + 255) & ~(size_t)255;
  float* H = (float*)(w + ofs2);          // n*128 f32 (h1, reused for h2)

  hipMemsetAsync(degcnt, 0, (size_t)n*sizeof(int), stream);
  if (!useRank) hipMemsetAsync(erank, 0, (size_t)n*sizeof(int), stream); // cursor
  hipMemsetAsync(out, 0, (size_t)out_size*sizeof(float), stream);

  const int nb = (n + 255)/256;
  const int m  = (e > n) ? e : n;
  const int mb = (m + 255)/256;
  const int eb = (e + 255)/256;

  detect_k<<<1, 256, 0, stream>>>((const unsigned int*)eidx, flag);
  ehist_k<<<mb, 256, 0, stream>>>(eidx, batchp, flag, degcnt, erank, useRank,
                                  batch32, n, e);
  gcnt_k<<<1, 256, 0, stream>>>(batch32, gcount, n, g);
  scan_a<<<nb, 256, 0, stream>>>(degcnt, rowptr, bsum, n);
  scan_b<<<1, 256, 0, stream>>>(bsum, nb);
  scan_c<<<(n + 1 + 255)/256, 256, 0, stream>>>(rowptr, bsum, degcnt, dinv, n, e);
  if (useRank)
    fillr_k<<<eb, 256, 0, stream>>>(eidx, flag, rowptr, erank, dinv, epack, e);
  else
    fill_k<<<eb, 256, 0, stream>>>(eidx, flag, rowptr, erank /*cursor*/, dinv, epack, e);

  const int gb = (n + 127)/128;
  gemm_k<128><<<gb, 512, 0, stream>>>(x, W1, HWb, n);
  agg_k<128><<<(n + 3)/4, 256, 0, stream>>>(HWb, dinv, rowptr, epack, b1, H, n);
  gemm_k<64><<<gb, 512, 0, stream>>>(H, W2, HWb, n);
  agg_k<64><<<(n + 3)/4, 256, 0, stream>>>(HWb, dinv, rowptr, epack, b2, H, n);

  int pw = (n + 127)/128;
  pool_k<<<(pw + 3)/4, 256, 0, stream>>>(H, batch32, out, n);
  fin_k<<<(out_size + 255)/256, 256, 0, stream>>>(out, gcount, out_size);
}

// Round 6
// 164.522 us; speedup vs baseline: 3.1854x; 1.2196x over previous
//
#include <hip/hip_runtime.h>

typedef float f4 __attribute__((ext_vector_type(4)));
typedef float f2 __attribute__((ext_vector_type(2)));
typedef short s8 __attribute__((ext_vector_type(8)));

union FU { unsigned u[4]; s8 s; };

// packed f32x2 -> bf16x2 (RNE) in one instruction
__device__ __forceinline__ unsigned cvtpk(float lo, float hi){
  unsigned r;
  asm("v_cvt_pk_bf16_f32 %0, %1, %2" : "=v"(r) : "v"(lo), "v"(hi));
  return r;
}

// ---- bf16 helpers ----
__device__ __forceinline__ float bflo(unsigned v){ return __uint_as_float(v << 16); }
__device__ __forceinline__ float bfhi(unsigned v){ return __uint_as_float(v & 0xFFFF0000u); }

// ---- index loader: handles int32 or int64 edge/batch arrays ----
__device__ __forceinline__ int ld_idx(const void* p, int i, int is64){
  if (is64) return (int)((const long long*)p)[i];
  return ((const int*)p)[i];
}

// Detect dtype of edge_index: int64 => every odd 32-bit word is zero.
__global__ void detect_k(const unsigned int* __restrict__ e_raw, int* __restrict__ flag){
  __shared__ int any;
  if (threadIdx.x == 0) any = 0;
  __syncthreads();
  int nz = 0;
  for (int i = threadIdx.x; i < 1024; i += 256) nz |= (e_raw[2*i + 1] != 0u);
  if (nz) any = 1;
  __syncthreads();
  if (threadIdx.x == 0) flag[0] = (any == 0) ? 1 : 0;   // 1 => int64
}

// edge histogram (captures per-edge rank within dst) + batch conversion.
__global__ void ehist_k(const void* __restrict__ eidx, const void* __restrict__ batchp,
                        const int* __restrict__ flag, int* __restrict__ degcnt,
                        int* __restrict__ erank, int wantRank,
                        int* __restrict__ batch32, int n, int e){
  int idx = blockIdx.x*256 + threadIdx.x;
  int is64 = flag[0];
  if (idx < e){
    int d = ld_idx(eidx, e + idx, is64);
    int r = atomicAdd(&degcnt[d], 1);
    if (wantRank) erank[idx] = r;
  }
  if (idx < n){
    batch32[idx] = (int)ld_idx(batchp, idx, is64);
  }
}

// graph sizes from sorted batch via binary search — zero atomics
__global__ void gcnt_k(const int* __restrict__ batch32, int* __restrict__ gcount,
                       int n, int g){
  __shared__ int starts[257];
  int t = threadIdx.x;
  if (t <= g){
    int lo = 0, hi = n;
    while (lo < hi){ int mid = (lo + hi) >> 1; if (batch32[mid] < t) lo = mid + 1; else hi = mid; }
    starts[t] = lo;
  }
  __syncthreads();
  if (t < g) gcount[t] = starts[t+1] - starts[t];
}

// ---- two-level exclusive scan of degcnt -> rowptr ----
__global__ void scan_a(const int* __restrict__ degcnt, int* __restrict__ rowptr,
                       int* __restrict__ bsum, int n){
  __shared__ int sh[256];
  int tid = threadIdx.x;
  int i = blockIdx.x*256 + tid;
  int v = (i < n) ? degcnt[i] : 0;
  sh[tid] = v; __syncthreads();
  for (int off = 1; off < 256; off <<= 1){
    int t = (tid >= off) ? sh[tid - off] : 0;
    __syncthreads();
    sh[tid] += t;
    __syncthreads();
  }
  if (i < n) rowptr[i] = sh[tid] - v;
  if (tid == 255) bsum[blockIdx.x] = sh[255];
}

__global__ void scan_b(int* __restrict__ bsum, int nb){
  __shared__ int sh[256];
  int tid = threadIdx.x;
  int v = (tid < nb) ? bsum[tid] : 0;
  sh[tid] = v; __syncthreads();
  for (int off = 1; off < 256; off <<= 1){
    int t = (tid >= off) ? sh[tid - off] : 0;
    __syncthreads();
    sh[tid] += t;
    __syncthreads();
  }
  if (tid < nb) bsum[tid] = sh[tid] - v;
}

// finalize rowptr + compute deg_inv_sqrt (fused)
__global__ void scan_c(int* __restrict__ rowptr, const int* __restrict__ bsum,
                       const int* __restrict__ degcnt, float* __restrict__ dinv,
                       int n, int e){
  int i = blockIdx.x*256 + threadIdx.x;
  if (i < n){
    rowptr[i] += bsum[i >> 8];
    dinv[i] = rsqrtf((float)degcnt[i] + 1.0f);
  }
  if (i == n) rowptr[n] = e;
}

// scatter edges into CSR order; pack (src, norm=dinv[s]*dinv[d]) per edge
__global__ void fillr_k(const void* __restrict__ eidx, const int* __restrict__ flag,
                        const int* __restrict__ rowptr, const int* __restrict__ erank,
                        const float* __restrict__ dinv, int2* __restrict__ epack, int e){
  int idx = blockIdx.x*256 + threadIdx.x;
  if (idx >= e) return;
  int is64 = flag[0];
  int s = ld_idx(eidx, idx, is64);
  int d = ld_idx(eidx, e + idx, is64);
  int2 pk; pk.x = s; pk.y = __float_as_int(dinv[s] * dinv[d]);
  epack[rowptr[d] + erank[idx]] = pk;
}

// fallback scatter (atomic cursor) if ws too small for erank
__global__ void fill_k(const void* __restrict__ eidx, const int* __restrict__ flag,
                       const int* __restrict__ rowptr, int* __restrict__ cursor,
                       const float* __restrict__ dinv, int2* __restrict__ epack, int e){
  int idx = blockIdx.x*256 + threadIdx.x;
  if (idx >= e) return;
  int is64 = flag[0];
  int s = ld_idx(eidx, idx, is64);
  int d = ld_idx(eidx, e + idx, is64);
  int pos = rowptr[d] + atomicAdd(&cursor[d], 1);
  int2 pk; pk.x = s; pk.y = __float_as_int(dinv[s] * dinv[d]);
  epack[pos] = pk;
}

// ---- MFMA GEMM: Yb[n,NC](bf16) = X[n,128](f32) @ W[128,NC](f32)
// 8 waves/block, M-tile=128, K=128. A staged in LDS (bf16, XOR-swizzled),
// B fragments held in registers per wave (W is L2-hot across all blocks).
template<int NC>
__global__ __launch_bounds__(512) void gemm_k(const float* __restrict__ X,
                                              const float* __restrict__ W,
                                              unsigned short* __restrict__ Yb, int n){
  constexpr int NCF = NC/16;      // col fragments: 8 (NC=128) or 4 (NC=64)
  constexpr int WPC = 8/NCF;      // wave row-groups: 1 or 2
  constexpr int RT  = 8/WPC;      // row tiles (16 rows) per wave: 8 or 4
  __shared__ int4 AldsV[2048];    // 32KB: A[row][k] bf16, byte ^= (row&7)<<4
  char* Alds = (char*)AldsV;
  const int tid  = threadIdx.x;
  const int wave = tid >> 6, lane = tid & 63;
  const int rb = blockIdx.x * 128;
  const f4* X4 = (const f4*)X;

  // B fragments: lane holds W[k][col], col = cbase+(lane&15), k = ks*32+kr0+j
  const int cbase = (wave % NCF) * 16;
  const int rt0   = (wave / NCF) * RT;
  const int col   = cbase + (lane & 15);
  const int kr0   = (lane >> 4) * 8;
  FU bu[4];
#pragma unroll
  for (int ks = 0; ks < 4; ++ks){
    float wv[8];
#pragma unroll
    for (int j = 0; j < 8; ++j) wv[j] = W[(size_t)(ks*32 + kr0 + j)*NC + col];
#pragma unroll
    for (int q = 0; q < 4; ++q) bu[ks].u[q] = cvtpk(wv[2*q], wv[2*q+1]);
  }

  // stage A tile (128 rows x 128 k) as bf16 into LDS
  for (int i = tid; i < 128*32; i += 512){
    int row = i >> 5, kq = i & 31;            // kq: float4 index along k
    int rsrc = rb + row; if (rsrc >= n) rsrc = n - 1;
    f4 xv = X4[(size_t)rsrc*32 + kq];
    unsigned lo = cvtpk(xv[0], xv[1]), hi = cvtpk(xv[2], xv[3]);
    int byte = (row*256 + kq*8) ^ ((row & 7) << 4);
    *reinterpret_cast<uint2*>(Alds + byte) = make_uint2(lo, hi);
  }
  __syncthreads();

  f4 acc[RT];
#pragma unroll
  for (int rt = 0; rt < RT; ++rt) acc[rt] = 0.0f;

#pragma unroll
  for (int rt = 0; rt < RT; ++rt){
    const int arow = (rt0 + rt)*16 + (lane & 15);
#pragma unroll
    for (int ks = 0; ks < 4; ++ks){
      int kb = ks*32 + kr0;
      int byte = (arow*256 + kb*2) ^ ((arow & 7) << 4);
      s8 a = *reinterpret_cast<const s8*>(Alds + byte);
      acc[rt] = __builtin_amdgcn_mfma_f32_16x16x32_bf16(a, bu[ks].s, acc[rt], 0, 0, 0);
    }
  }

  // C store: col = lane&15 offset, row = 4*(lane>>4) + r  (verified layout)
#pragma unroll
  for (int rt = 0; rt < RT; ++rt){
    int rowb = rb + (rt0 + rt)*16 + 4*(lane >> 4);
#pragma unroll
    for (int r = 0; r < 4; ++r){
      int row = rowb + r;
      if (row < n) Yb[(size_t)row*NC + col] = (unsigned short)cvtpk(acc[rt][r], acc[rt][r]);
    }
  }
}

// ---- CSR aggregation + bias + relu: one wave per node, bf16 gathers.
// Unroll-by-8 load-then-FMA so 8 gathers are in flight per wave (MLP).
template<int NC>
__global__ __launch_bounds__(256) void agg_k(const unsigned short* __restrict__ HWb,
                                             const float* __restrict__ dinv,
                                             const int* __restrict__ rowptr,
                                             const int2* __restrict__ epack,
                                             const float* __restrict__ bias,
                                             float* __restrict__ Hout, int n){
  int wid  = (blockIdx.x*256 + threadIdx.x) >> 6;
  int lane = threadIdx.x & 63;
  if (wid >= n) return;
  wid = __builtin_amdgcn_readfirstlane(wid);        // wave-uniform -> SGPR
  float di = dinv[wid];
  float di2 = di * di;
  int beg = __builtin_amdgcn_readfirstlane(rowptr[wid]);
  int end = __builtin_amdgcn_readfirstlane(rowptr[wid + 1]);
  if (NC == 128){
    unsigned sv = ((const unsigned*)(HWb + (size_t)wid*128))[lane];
    f2 acc;
    acc[0] = bflo(sv) * di2;
    acc[1] = bfhi(sv) * di2;
    int j = beg;
    for (; j + 8 <= end; j += 8){
      unsigned v[8]; float wt[8];
#pragma unroll
      for (int t = 0; t < 8; ++t){
        int2 pk = epack[j + t];
        wt[t] = __int_as_float(pk.y);
        v[t] = ((const unsigned*)(HWb + (size_t)pk.x*128))[lane];
      }
#pragma unroll
      for (int t = 0; t < 8; ++t){
        acc[0] += bflo(v[t]) * wt[t];
        acc[1] += bfhi(v[t]) * wt[t];
      }
    }
    if (j + 4 <= end){
      unsigned v[4]; float wt[4];
#pragma unroll
      for (int t = 0; t < 4; ++t){
        int2 pk = epack[j + t];
        wt[t] = __int_as_float(pk.y);
        v[t] = ((const unsigned*)(HWb + (size_t)pk.x*128))[lane];
      }
#pragma unroll
      for (int t = 0; t < 4; ++t){
        acc[0] += bflo(v[t]) * wt[t];
        acc[1] += bfhi(v[t]) * wt[t];
      }
      j += 4;
    }
    for (; j < end; ++j){
      int2 pk = epack[j];
      float wt = __int_as_float(pk.y);
      unsigned v = ((const unsigned*)(HWb + (size_t)pk.x*128))[lane];
      acc[0] += bflo(v) * wt;
      acc[1] += bfhi(v) * wt;
    }
    f2 bb = ((const f2*)bias)[lane];
    acc += bb;
    acc[0] = fmaxf(acc[0], 0.0f);
    acc[1] = fmaxf(acc[1], 0.0f);
    ((f2*)Hout)[(size_t)wid*64 + lane] = acc;
  } else {
    float acc = bflo((unsigned)HWb[(size_t)wid*64 + lane]) * di2;
    int j = beg;
    for (; j + 8 <= end; j += 8){
      unsigned v[8]; float wt[8];
#pragma unroll
      for (int t = 0; t < 8; ++t){
        int2 pk = epack[j + t];
        wt[t] = __int_as_float(pk.y);
        v[t] = (unsigned)HWb[(size_t)pk.x*64 + lane];
      }
#pragma unroll
      for (int t = 0; t < 8; ++t) acc += bflo(v[t]) * wt[t];
    }
    if (j + 4 <= end){
      unsigned v[4]; float wt[4];
#pragma unroll
      for (int t = 0; t < 4; ++t){
        int2 pk = epack[j + t];
        wt[t] = __int_as_float(pk.y);
        v[t] = (unsigned)HWb[(size_t)pk.x*64 + lane];
      }
#pragma unroll
      for (int t = 0; t < 4; ++t) acc += bflo(v[t]) * wt[t];
      j += 4;
    }
    for (; j < end; ++j){
      int2 pk = epack[j];
      acc += bflo((unsigned)HWb[(size_t)pk.x*64 + lane]) * __int_as_float(pk.y);
    }
    acc = fmaxf(acc + bias[lane], 0.0f);
    Hout[(size_t)wid*64 + lane] = acc;
  }
}

// ---- mean pool: 8 nodes per wave, unrolled independent loads, run-length
// atomics (batch sorted => typically 1 atomic per wave) ----
__global__ __launch_bounds__(256) void pool_k(const float* __restrict__ H2,
                                              const int* __restrict__ batch32,
                                              float* __restrict__ outsum, int n){
  int wid  = (blockIdx.x*256 + threadIdx.x) >> 6;
  int lane = threadIdx.x & 63;
  int start = wid * 8;
  if (start >= n) return;
  int cnt = min(8, n - start);
  float v[8]; int b[8];
#pragma unroll
  for (int t = 0; t < 8; ++t){
    int i = start + t; if (i >= n) i = n - 1;
    v[t] = H2[(size_t)i*64 + lane];
    b[t] = batch32[i];
  }
  float acc = 0.0f;
  int gcur = b[0];
#pragma unroll
  for (int t = 0; t < 8; ++t){
    if (t < cnt){
      if (b[t] != gcur){
        unsafeAtomicAdd(&outsum[gcur*64 + lane], acc);
        acc = 0.0f; gcur = b[t];
      }
      acc += v[t];
    }
  }
  unsafeAtomicAdd(&outsum[gcur*64 + lane], acc);
}

__global__ void fin_k(float* __restrict__ out, const int* __restrict__ gcount, int total){
  int idx = blockIdx.x*256 + threadIdx.x;
  if (idx < total){
    int gidx = idx >> 6;
    float c = (float)gcount[gidx];
    out[idx] = out[idx] / fmaxf(c, 1.0f);
  }
}

extern "C" void kernel_launch(void* const* d_in, const int* in_sizes, int n_in,
                              void* d_out, int out_size, void* d_ws, size_t ws_size,
                              hipStream_t stream){
  const float* x    = (const float*)d_in[0];
  const float* W1   = (const float*)d_in[1];
  const float* b1   = (const float*)d_in[2];
  const float* W2   = (const float*)d_in[3];
  const float* b2   = (const float*)d_in[4];
  const void*  eidx = d_in[5];
  const void*  batchp = d_in[6];
  const int n = in_sizes[0] / 128;    // 50000
  const int e = in_sizes[5] / 2;      // 800000
  const int g = out_size / 64;        // 64 graphs
  float* out = (float*)d_out;

  // ---- workspace layout ----
  char* w = (char*)d_ws;
  int* flag    = (int*)w;                 // 64 ints
  int* degcnt  = flag + 64;               // n (memset 0)
  int* gcount  = degcnt + n;              // g
  int* rowptr  = gcount + g;              // n+1
  int* bsum    = rowptr + (n + 1);        // 256
  size_t fixedI = 64 + (size_t)n + g + (n + 1) + 256;
  size_t needA  = (fixedI + (size_t)e + 2*(size_t)e + n + n) * 4 + 512
                + (size_t)n * 128 * 2        /* HWb bf16 */
                + (size_t)n * 128 * 4;       /* H f32 */
  const int useRank = (ws_size >= needA);
  int*  erank  = bsum + 256;              // e ints (A) or n ints as cursor (B)
  int2* epack  = (int2*)(erank + (useRank ? e : n));   // e int2
  int* batch32 = (int*)(epack + e);       // n
  float* dinv  = (float*)(batch32 + n);   // n
  size_t ofs = (size_t)((char*)(dinv + n) - w);
  ofs = (ofs + 255) & ~(size_t)255;
  unsigned short* HWb = (unsigned short*)(w + ofs);   // n*128 bf16 (both layers)
  size_t ofs2 = ofs + (size_t)n * 128 * 2;
  ofs2 = (ofs2 + 255) & ~(size_t)255;
  float* H = (float*)(w + ofs2);          // n*128 f32 (h1, reused for h2)

  hipMemsetAsync(degcnt, 0, (size_t)n*sizeof(int), stream);
  if (!useRank) hipMemsetAsync(erank, 0, (size_t)n*sizeof(int), stream); // cursor
  hipMemsetAsync(out, 0, (size_t)out_size*sizeof(float), stream);

  const int nb = (n + 255)/256;
  const int m  = (e > n) ? e : n;
  const int mb = (m + 255)/256;
  const int eb = (e + 255)/256;

  detect_k<<<1, 256, 0, stream>>>((const unsigned int*)eidx, flag);
  ehist_k<<<mb, 256, 0, stream>>>(eidx, batchp, flag, degcnt, erank, useRank,
                                  batch32, n, e);
  gcnt_k<<<1, 256, 0, stream>>>(batch32, gcount, n, g);
  scan_a<<<nb, 256, 0, stream>>>(degcnt, rowptr, bsum, n);
  scan_b<<<1, 256, 0, stream>>>(bsum, nb);
  scan_c<<<(n + 1 + 255)/256, 256, 0, stream>>>(rowptr, bsum, degcnt, dinv, n, e);
  if (useRank)
    fillr_k<<<eb, 256, 0, stream>>>(eidx, flag, rowptr, erank, dinv, epack, e);
  else
    fill_k<<<eb, 256, 0, stream>>>(eidx, flag, rowptr, erank /*cursor*/, dinv, epack, e);

  const int gb = (n + 127)/128;
  gemm_k<128><<<gb, 512, 0, stream>>>(x, W1, HWb, n);
  agg_k<128><<<(n + 3)/4, 256, 0, stream>>>(HWb, dinv, rowptr, epack, b1, H, n);
  gemm_k<64><<<gb, 512, 0, stream>>>(H, W2, HWb, n);
  agg_k<64><<<(n + 3)/4, 256, 0, stream>>>(HWb, dinv, rowptr, epack, b2, H, n);

  int pw = (n + 7)/8;   // one wave per 8-node chunk
  pool_k<<<(pw + 3)/4, 256, 0, stream>>>(H, batch32, out, n);
  fin_k<<<(out_size + 255)/256, 256, 0, stream>>>(out, gcount, out_size);
}

// Round 7
// 160.926 us; speedup vs baseline: 3.2566x; 1.0223x over previous
//
#include <hip/hip_runtime.h>

typedef float f4 __attribute__((ext_vector_type(4)));
typedef float f2 __attribute__((ext_vector_type(2)));
typedef short s8 __attribute__((ext_vector_type(8)));

union FU { unsigned u[4]; s8 s; };

// packed f32x2 -> bf16x2 (RNE) in one instruction
__device__ __forceinline__ unsigned cvtpk(float lo, float hi){
  unsigned r;
  asm("v_cvt_pk_bf16_f32 %0, %1, %2" : "=v"(r) : "v"(lo), "v"(hi));
  return r;
}

// ---- bf16 helpers ----
__device__ __forceinline__ float bflo(unsigned v){ return __uint_as_float(v << 16); }
__device__ __forceinline__ float bfhi(unsigned v){ return __uint_as_float(v & 0xFFFF0000u); }

// ---- index loader: handles int32 or int64 edge/batch arrays ----
__device__ __forceinline__ int ld_idx(const void* p, int i, int is64){
  if (is64) return (int)((const long long*)p)[i];
  return ((const int*)p)[i];
}

// wave-level dtype detect (1 => int64): for int64 every odd 32-bit word of
// edge_index is 0 (values < n). For int32 odd words are random src values.
// Must be called by all lanes of the wave (uses ballot).
__device__ __forceinline__ int detect64(const unsigned* __restrict__ e_raw, int e){
  int lane = threadIdx.x & 63;
  int lim = (e < 1024) ? e : 1024;
  int nz = 0;
  for (int i = lane; i < lim; i += 64) nz |= (e_raw[2*i + 1] != 0u);
  return (__ballot(nz != 0) == 0ull) ? 1 : 0;
}

// ---- MFMA GEMM body: Yb[n,NC](bf16) = X[n,128](f32) @ W[128,NC](f32)
// 8 waves/block, M-tile=128, K=128. A staged in LDS (bf16, XOR-swizzled),
// B fragments held in registers per wave (W is L2-hot across all blocks).
template<int NC>
__device__ __forceinline__ void gemm_body(const float* __restrict__ X,
                                          const float* __restrict__ W,
                                          unsigned short* __restrict__ Yb,
                                          int n, int blk, char* Alds){
  constexpr int NCF = NC/16;      // col fragments: 8 (NC=128) or 4 (NC=64)
  constexpr int WPC = 8/NCF;      // wave row-groups: 1 or 2
  constexpr int RT  = 8/WPC;      // row tiles (16 rows) per wave: 8 or 4
  const int tid  = threadIdx.x;
  const int wave = tid >> 6, lane = tid & 63;
  const int rb = blk * 128;
  const f4* X4 = (const f4*)X;

  const int cbase = (wave % NCF) * 16;
  const int rt0   = (wave / NCF) * RT;
  const int col   = cbase + (lane & 15);
  const int kr0   = (lane >> 4) * 8;
  FU bu[4];
#pragma unroll
  for (int ks = 0; ks < 4; ++ks){
    float wv[8];
#pragma unroll
    for (int j = 0; j < 8; ++j) wv[j] = W[(size_t)(ks*32 + kr0 + j)*NC + col];
#pragma unroll
    for (int q = 0; q < 4; ++q) bu[ks].u[q] = cvtpk(wv[2*q], wv[2*q+1]);
  }

  for (int i = tid; i < 128*32; i += 512){
    int row = i >> 5, kq = i & 31;            // kq: float4 index along k
    int rsrc = rb + row; if (rsrc >= n) rsrc = n - 1;
    f4 xv = X4[(size_t)rsrc*32 + kq];
    unsigned lo = cvtpk(xv[0], xv[1]), hi = cvtpk(xv[2], xv[3]);
    int byte = (row*256 + kq*8) ^ ((row & 7) << 4);
    *reinterpret_cast<uint2*>(Alds + byte) = make_uint2(lo, hi);
  }
  __syncthreads();

  f4 acc[RT];
#pragma unroll
  for (int rt = 0; rt < RT; ++rt) acc[rt] = 0.0f;

#pragma unroll
  for (int rt = 0; rt < RT; ++rt){
    const int arow = (rt0 + rt)*16 + (lane & 15);
#pragma unroll
    for (int ks = 0; ks < 4; ++ks){
      int kb = ks*32 + kr0;
      int byte = (arow*256 + kb*2) ^ ((arow & 7) << 4);
      s8 a = *reinterpret_cast<const s8*>(Alds + byte);
      acc[rt] = __builtin_amdgcn_mfma_f32_16x16x32_bf16(a, bu[ks].s, acc[rt], 0, 0, 0);
    }
  }

  // C store: col = lane&15, row = 4*(lane>>4) + r (verified layout)
#pragma unroll
  for (int rt = 0; rt < RT; ++rt){
    int rowb = rb + (rt0 + rt)*16 + 4*(lane >> 4);
#pragma unroll
    for (int r = 0; r < 4; ++r){
      int row = rowb + r;
      if (row < n) Yb[(size_t)row*NC + col] = (unsigned short)cvtpk(acc[rt][r], acc[rt][r]);
    }
  }
}

template<int NC>
__global__ __launch_bounds__(512) void gemm_k(const float* __restrict__ X,
                                              const float* __restrict__ W,
                                              unsigned short* __restrict__ Yb, int n){
  __shared__ int4 AldsV[2048];    // 32KB
  gemm_body<NC>(X, W, Yb, n, blockIdx.x, (char*)AldsV);
}

// ---- fused: gemm1 (blocks < GB) || edge-histogram + batch convert (rest).
// The two are data-independent; hist is atomic-throughput bound with idle
// VALU/MFMA pipes, so gemm1 hides inside its window.
__global__ __launch_bounds__(512) void fused1_k(const float* __restrict__ X,
                                                const float* __restrict__ W1,
                                                unsigned short* __restrict__ Yb,
                                                const void* __restrict__ eidx,
                                                const void* __restrict__ batchp,
                                                int* __restrict__ degcnt, int dshift,
                                                int* __restrict__ erank, int wantRank,
                                                int* __restrict__ batch32,
                                                int n, int e, int GB){
  __shared__ int4 AldsV[2048];
  if ((int)blockIdx.x < GB){
    gemm_body<128>(X, W1, Yb, n, blockIdx.x, (char*)AldsV);
    return;
  }
  int idx = ((int)blockIdx.x - GB)*512 + threadIdx.x;
  int is64 = detect64((const unsigned*)eidx, e);
  if (idx < e){
    int d = ld_idx(eidx, e + idx, is64);
    int r = atomicAdd(&degcnt[(size_t)d << dshift], 1);
    if (wantRank) erank[idx] = r;
  }
  if (idx < n){
    batch32[idx] = ld_idx(batchp, idx, is64);
  }
}

// ---- scan level 1: block-local exclusive scan of degcnt -> rowptr ----
__global__ void scan_a(const int* __restrict__ degcnt, int dshift,
                       int* __restrict__ rowptr, int* __restrict__ bsum, int n){
  __shared__ int sh[256];
  int tid = threadIdx.x;
  int i = blockIdx.x*256 + tid;
  int v = (i < n) ? degcnt[(size_t)i << dshift] : 0;
  sh[tid] = v; __syncthreads();
  for (int off = 1; off < 256; off <<= 1){
    int t = (tid >= off) ? sh[tid - off] : 0;
    __syncthreads();
    sh[tid] += t;
    __syncthreads();
  }
  if (i < n) rowptr[i] = sh[tid] - v;
  if (tid == 255) bsum[blockIdx.x] = sh[255];
}

// ---- scan level 2 folded in: every block redundantly scans bsum[256],
// finalizes rowptr, computes dinv; block 0 zeroes outsum. ----
__global__ void scan_cb(int* __restrict__ rowptr, const int* __restrict__ bsum,
                        int nb, const int* __restrict__ degcnt, int dshift,
                        float* __restrict__ dinv, float* __restrict__ outsum,
                        int totalOut, int n, int e){
  __shared__ int shI[256], shO[256];
  int tid = threadIdx.x;
  int v = (tid < nb) ? bsum[tid] : 0;
  shO[tid] = v; shI[tid] = v; __syncthreads();
  for (int off = 1; off < 256; off <<= 1){
    int t = (tid >= off) ? shI[tid - off] : 0;
    __syncthreads();
    shI[tid] += t;
    __syncthreads();
  }
  int i = blockIdx.x*256 + tid;
  if (i < n){
    int gb = i >> 8;
    rowptr[i] += shI[gb] - shO[gb];   // exclusive block offset
    dinv[i] = rsqrtf((float)degcnt[(size_t)i << dshift] + 1.0f);
  }
  if (i == n) rowptr[n] = e;
  if (blockIdx.x == 0){
    for (int k = tid; k < totalOut; k += 256) outsum[k] = 0.0f;
  }
}

// scatter edges into CSR order; pack (src, norm=dinv[s]*dinv[d]) per edge
__global__ __launch_bounds__(512) void fillr_k(const void* __restrict__ eidx,
                                               const int* __restrict__ rowptr,
                                               const int* __restrict__ erank,
                                               const float* __restrict__ dinv,
                                               int2* __restrict__ epack, int e){
  int idx = blockIdx.x*512 + threadIdx.x;
  int is64 = detect64((const unsigned*)eidx, e);
  if (idx >= e) return;
  int s = ld_idx(eidx, idx, is64);
  int d = ld_idx(eidx, e + idx, is64);
  int2 pk; pk.x = s; pk.y = __float_as_int(dinv[s] * dinv[d]);
  epack[rowptr[d] + erank[idx]] = pk;
}

// fallback scatter (atomic cursor) if ws too small for erank
__global__ __launch_bounds__(512) void fill_k(const void* __restrict__ eidx,
                                              const int* __restrict__ rowptr,
                                              int* __restrict__ cursor,
                                              const float* __restrict__ dinv,
                                              int2* __restrict__ epack, int e){
  int idx = blockIdx.x*512 + threadIdx.x;
  int is64 = detect64((const unsigned*)eidx, e);
  if (idx >= e) return;
  int s = ld_idx(eidx, idx, is64);
  int d = ld_idx(eidx, e + idx, is64);
  int pos = rowptr[d] + atomicAdd(&cursor[d], 1);
  int2 pk; pk.x = s; pk.y = __float_as_int(dinv[s] * dinv[d]);
  epack[pos] = pk;
}

// ---- CSR aggregation + bias + relu: one wave per node, bf16 gathers.
// Unroll-by-8 load-then-FMA so 8 gathers are in flight per wave (MLP).
template<int NC>
__global__ __launch_bounds__(256) void agg_k(const unsigned short* __restrict__ HWb,
                                             const float* __restrict__ dinv,
                                             const int* __restrict__ rowptr,
                                             const int2* __restrict__ epack,
                                             const float* __restrict__ bias,
                                             float* __restrict__ Hout, int n){
  int wid  = (blockIdx.x*256 + threadIdx.x) >> 6;
  int lane = threadIdx.x & 63;
  if (wid >= n) return;
  wid = __builtin_amdgcn_readfirstlane(wid);        // wave-uniform -> SGPR
  float di = dinv[wid];
  float di2 = di * di;
  int beg = __builtin_amdgcn_readfirstlane(rowptr[wid]);
  int end = __builtin_amdgcn_readfirstlane(rowptr[wid + 1]);
  if (NC == 128){
    unsigned sv = ((const unsigned*)(HWb + (size_t)wid*128))[lane];
    f2 acc;
    acc[0] = bflo(sv) * di2;
    acc[1] = bfhi(sv) * di2;
    int j = beg;
    for (; j + 8 <= end; j += 8){
      unsigned v[8]; float wt[8];
#pragma unroll
      for (int t = 0; t < 8; ++t){
        int2 pk = epack[j + t];
        wt[t] = __int_as_float(pk.y);
        v[t] = ((const unsigned*)(HWb + (size_t)pk.x*128))[lane];
      }
#pragma unroll
      for (int t = 0; t < 8; ++t){
        acc[0] += bflo(v[t]) * wt[t];
        acc[1] += bfhi(v[t]) * wt[t];
      }
    }
    if (j + 4 <= end){
      unsigned v[4]; float wt[4];
#pragma unroll
      for (int t = 0; t < 4; ++t){
        int2 pk = epack[j + t];
        wt[t] = __int_as_float(pk.y);
        v[t] = ((const unsigned*)(HWb + (size_t)pk.x*128))[lane];
      }
#pragma unroll
      for (int t = 0; t < 4; ++t){
        acc[0] += bflo(v[t]) * wt[t];
        acc[1] += bfhi(v[t]) * wt[t];
      }
      j += 4;
    }
    for (; j < end; ++j){
      int2 pk = epack[j];
      float wt = __int_as_float(pk.y);
      unsigned v = ((const unsigned*)(HWb + (size_t)pk.x*128))[lane];
      acc[0] += bflo(v) * wt;
      acc[1] += bfhi(v) * wt;
    }
    f2 bb = ((const f2*)bias)[lane];
    acc += bb;
    acc[0] = fmaxf(acc[0], 0.0f);
    acc[1] = fmaxf(acc[1], 0.0f);
    ((f2*)Hout)[(size_t)wid*64 + lane] = acc;
  } else {
    float acc = bflo((unsigned)HWb[(size_t)wid*64 + lane]) * di2;
    int j = beg;
    for (; j + 8 <= end; j += 8){
      unsigned v[8]; float wt[8];
#pragma unroll
      for (int t = 0; t < 8; ++t){
        int2 pk = epack[j + t];
        wt[t] = __int_as_float(pk.y);
        v[t] = (unsigned)HWb[(size_t)pk.x*64 + lane];
      }
#pragma unroll
      for (int t = 0; t < 8; ++t) acc += bflo(v[t]) * wt[t];
    }
    if (j + 4 <= end){
      unsigned v[4]; float wt[4];
#pragma unroll
      for (int t = 0; t < 4; ++t){
        int2 pk = epack[j + t];
        wt[t] = __int_as_float(pk.y);
        v[t] = (unsigned)HWb[(size_t)pk.x*64 + lane];
      }
#pragma unroll
      for (int t = 0; t < 4; ++t) acc += bflo(v[t]) * wt[t];
      j += 4;
    }
    for (; j < end; ++j){
      int2 pk = epack[j];
      acc += bflo((unsigned)HWb[(size_t)pk.x*64 + lane]) * __int_as_float(pk.y);
    }
    acc = fmaxf(acc + bias[lane], 0.0f);
    Hout[(size_t)wid*64 + lane] = acc;
  }
}

// ---- mean pool: 8 nodes per wave, unrolled independent loads, run-length
// atomics into ws outsum (batch sorted => typically 1 atomic per wave) ----
__global__ __launch_bounds__(256) void pool_k(const float* __restrict__ H2,
                                              const int* __restrict__ batch32,
                                              float* __restrict__ outsum, int n){
  int wid  = (blockIdx.x*256 + threadIdx.x) >> 6;
  int lane = threadIdx.x & 63;
  int start = wid * 8;
  if (start >= n) return;
  int cnt = min(8, n - start);
  float v[8]; int b[8];
#pragma unroll
  for (int t = 0; t < 8; ++t){
    int i = start + t; if (i >= n) i = n - 1;
    v[t] = H2[(size_t)i*64 + lane];
    b[t] = batch32[i];
  }
  float acc = 0.0f;
  int gcur = b[0];
#pragma unroll
  for (int t = 0; t < 8; ++t){
    if (t < cnt){
      if (b[t] != gcur){
        unsafeAtomicAdd(&outsum[gcur*64 + lane], acc);
        acc = 0.0f; gcur = b[t];
      }
      acc += v[t];
    }
  }
  unsafeAtomicAdd(&outsum[gcur*64 + lane], acc);
}

// ---- finalize: graph sizes via binary search on sorted batch + divide ----
__global__ void fin_k(const float* __restrict__ outsum,
                      const int* __restrict__ batch32,
                      float* __restrict__ out, int n, int g){
  __shared__ int starts[257];
  int t = threadIdx.x;
  if (t <= g){
    int lo = 0, hi = n;
    while (lo < hi){ int mid = (lo + hi) >> 1; if (batch32[mid] < t) lo = mid + 1; else hi = mid; }
    starts[t] = lo;
  }
  __syncthreads();
  for (int idx = t; idx < (g << 6); idx += 256){
    int gi = idx >> 6;
    float c = (float)(starts[gi + 1] - starts[gi]);
    out[idx] = outsum[idx] / fmaxf(c, 1.0f);
  }
}

extern "C" void kernel_launch(void* const* d_in, const int* in_sizes, int n_in,
                              void* d_out, int out_size, void* d_ws, size_t ws_size,
                              hipStream_t stream){
  const float* x    = (const float*)d_in[0];
  const float* W1   = (const float*)d_in[1];
  const float* b1   = (const float*)d_in[2];
  const float* W2   = (const float*)d_in[3];
  const float* b2   = (const float*)d_in[4];
  const void*  eidx = d_in[5];
  const void*  batchp = d_in[6];
  const int n = in_sizes[0] / 128;    // 50000
  const int e = in_sizes[5] / 2;      // 800000
  const int g = out_size / 64;        // 64 graphs
  float* out = (float*)d_out;

  // ---- workspace layout (sizing for dshift=4, falls back gracefully) ----
  char* w = (char*)d_ws;
  // ints: degcnt n<<ds | rowptr n+1 | bsum 256 | erank e (or cursor n) |
  //       epack 2e | batch32 n | dinv n | outsum totalOut
  size_t needFull = ((size_t)n*16 + (n+1) + 256 + (size_t)e + 2*(size_t)e + n + n
                     + out_size) * 4 + 1024
                  + (size_t)n * 128 * 2      /* HWb bf16 */
                  + (size_t)n * 128 * 4;     /* H f32 */
  size_t needRank = needFull - (size_t)n*15*4;  // dshift=0 variant
  const int dshift  = (ws_size >= needFull) ? 4 : 0;
  const int useRank = (ws_size >= needRank);

  int* degcnt  = (int*)w;                          // n<<dshift
  int* rowptr  = degcnt + ((size_t)n << dshift);   // n+1
  int* bsum    = rowptr + (n + 1);                 // 256
  int*  erank  = bsum + 256;                       // e (or n as cursor)
  int2* epack  = (int2*)(erank + (useRank ? e : n));
  int* batch32 = (int*)(epack + e);                // n
  float* dinv  = (float*)(batch32 + n);            // n
  float* outsum = dinv + n;                        // out_size
  size_t ofs = (size_t)((char*)(outsum + out_size) - w);
  ofs = (ofs + 255) & ~(size_t)255;
  unsigned short* HWb = (unsigned short*)(w + ofs);   // n*128 bf16
  size_t ofs2 = ofs + (size_t)n * 128 * 2;
  ofs2 = (ofs2 + 255) & ~(size_t)255;
  float* H = (float*)(w + ofs2);                   // n*128 f32

  hipMemsetAsync(degcnt, 0, ((size_t)n << dshift)*sizeof(int), stream);
  if (!useRank) hipMemsetAsync(erank, 0, (size_t)n*sizeof(int), stream); // cursor

  const int nb = (n + 255)/256;
  const int m  = (e > n) ? e : n;
  const int GB = (n + 127)/128;           // gemm blocks
  const int HB = (m + 511)/512;           // hist blocks

  fused1_k<<<GB + HB, 512, 0, stream>>>(x, W1, HWb, eidx, batchp,
                                        degcnt, dshift, erank, useRank,
                                        batch32, n, e, GB);
  scan_a<<<nb, 256, 0, stream>>>(degcnt, dshift, rowptr, bsum, n);
  scan_cb<<<(n + 1 + 255)/256, 256, 0, stream>>>(rowptr, bsum, nb, degcnt, dshift,
                                                 dinv, outsum, out_size, n, e);
  if (useRank)
    fillr_k<<<(e + 511)/512, 512, 0, stream>>>(eidx, rowptr, erank, dinv, epack, e);
  else
    fill_k<<<(e + 511)/512, 512, 0, stream>>>(eidx, rowptr, erank /*cursor*/, dinv, epack, e);

  agg_k<128><<<(n + 3)/4, 256, 0, stream>>>(HWb, dinv, rowptr, epack, b1, H, n);
  gemm_k<64><<<GB, 512, 0, stream>>>(H, W2, HWb, n);
  agg_k<64><<<(n + 3)/4, 256, 0, stream>>>(HWb, dinv, rowptr, epack, b2, H, n);

  int pw = (n + 7)/8;   // one wave per 8-node chunk
  pool_k<<<(pw + 3)/4, 256, 0, stream>>>(H, batch32, outsum, n);
  fin_k<<<1, 256, 0, stream>>>(outsum, batch32, out, n, g);
}